// Round 6
// baseline (452.566 us; speedup 1.0000x reference)
//
#include <hip/hip_runtime.h>
#include <math.h>

#define H 128
#define KE 256      // MFMA K for edge GEMM1 (k=256,257 via fp32 rank-1 update)
#define KN 256      // node GEMM1 K (2H)

typedef __attribute__((ext_vector_type(8))) short bf16x8;
typedef __attribute__((ext_vector_type(4))) float f32x4;

__device__ __forceinline__ float silu_f(float x) { return x / (1.0f + __expf(-x)); }

__device__ __forceinline__ unsigned short f2bf(float f) {
    unsigned int u = __float_as_uint(f);
    unsigned int r = u + 0x7FFFu + ((u >> 16) & 1u);
    return (unsigned short)(r >> 16);
}

// load 8 consecutive fp32, convert to bf16x8 fragment
__device__ __forceinline__ bf16x8 ld_cvt8(const float* p) {
    float4 f0 = ((const float4*)p)[0];
    float4 f1 = ((const float4*)p)[1];
    union { bf16x8 v; unsigned short u[8]; } pk;
    pk.u[0] = f2bf(f0.x); pk.u[1] = f2bf(f0.y); pk.u[2] = f2bf(f0.z); pk.u[3] = f2bf(f0.w);
    pk.u[4] = f2bf(f1.x); pk.u[5] = f2bf(f1.y); pk.u[6] = f2bf(f1.z); pk.u[7] = f2bf(f1.w);
    return pk.v;
}

// -------------------- prep: h fp32 -> bf16 (vectorized x4) --------------------
__global__ void prep_h(const float* __restrict__ x, unsigned short* __restrict__ y, int n4) {
    int i = blockIdx.x * 256 + threadIdx.x;
    if (i < n4) {
        float4 f = ((const float4*)x)[i];
        ushort4 o;
        o.x = f2bf(f.x); o.y = f2bf(f.y); o.z = f2bf(f.z); o.w = f2bf(f.w);
        ((ushort4*)y)[i] = o;
    }
}

// ---- prep all weights: W[K][128] fp32 -> fragment-linear Wf[(kb*8+nt)*64+lane][8] ----
__global__ void prep_w_all(
    const float* __restrict__ eW1, const float* __restrict__ eW2,
    const float* __restrict__ cW1, const float* __restrict__ nW1,
    const float* __restrict__ nW2,
    unsigned short* __restrict__ eW1f, unsigned short* __restrict__ eW2f,
    unsigned short* __restrict__ cW1f, unsigned short* __restrict__ nW1f,
    unsigned short* __restrict__ nW2f)
{
    const float* W; unsigned short* Wf; int nfrag;
    switch (blockIdx.y) {
        case 0:  W = eW1; Wf = eW1f; nfrag = 8 * 8 * 64; break;
        case 1:  W = eW2; Wf = eW2f; nfrag = 4 * 8 * 64; break;
        case 2:  W = cW1; Wf = cW1f; nfrag = 4 * 8 * 64; break;
        case 3:  W = nW1; Wf = nW1f; nfrag = 8 * 8 * 64; break;
        default: W = nW2; Wf = nW2f; nfrag = 4 * 8 * 64; break;
    }
    int f = blockIdx.x * 64 + threadIdx.x;
    if (f >= nfrag) return;
    int kb = f >> 9;
    int rem = f & 511;
    int nt = rem >> 6, lane = rem & 63;
    int quad = lane >> 4, l15 = lane & 15;
    int n = nt * 16 + l15, k0 = kb * 32 + quad * 8;
    union { bf16x8 v; unsigned short u[8]; } pk;
    #pragma unroll
    for (int j = 0; j < 8; ++j) pk.u[j] = f2bf(W[(size_t)(k0 + j) * H + n]);
    *(bf16x8*)&Wf[(size_t)f * 8] = pk.v;
}

// ---- dual-tile epilogue: bias + LN + SiLU; results left in acc, bf16 copies in LDS ----
__device__ __forceinline__ void ln_silu_store2(
    f32x4* accA, f32x4* accB,
    const float* __restrict__ bias, const float* __restrict__ g,
    const float* __restrict__ be,
    unsigned short* dA, unsigned short* dB, int l15, int quad)
{
    float sA[4] = {0,0,0,0}, qA[4] = {0,0,0,0};
    float sB[4] = {0,0,0,0}, qB[4] = {0,0,0,0};
    #pragma unroll
    for (int nt = 0; nt < 8; ++nt) {
        float b = bias[nt * 16 + l15];
        #pragma unroll
        for (int r = 0; r < 4; ++r) {
            float xA = accA[nt][r] + b; accA[nt][r] = xA; sA[r] += xA; qA[r] += xA * xA;
            float xB = accB[nt][r] + b; accB[nt][r] = xB; sB[r] += xB; qB[r] += xB * xB;
        }
    }
    #pragma unroll
    for (int m = 1; m <= 8; m <<= 1) {
        #pragma unroll
        for (int r = 0; r < 4; ++r) {
            sA[r] += __shfl_xor(sA[r], m, 64); qA[r] += __shfl_xor(qA[r], m, 64);
            sB[r] += __shfl_xor(sB[r], m, 64); qB[r] += __shfl_xor(qB[r], m, 64);
        }
    }
    #pragma unroll
    for (int r = 0; r < 4; ++r) {
        float muA = sA[r] * 0.0078125f, vA = qA[r] * 0.0078125f - muA * muA;
        sA[r] = muA; qA[r] = rsqrtf(vA + 1e-5f);
        float muB = sB[r] * 0.0078125f, vB = qB[r] * 0.0078125f - muB * muB;
        sB[r] = muB; qB[r] = rsqrtf(vB + 1e-5f);
    }
    #pragma unroll
    for (int nt = 0; nt < 8; ++nt) {
        float gg = g[nt * 16 + l15], bb = be[nt * 16 + l15];
        int oct = nt * 2 + (l15 >> 3), j = l15 & 7;
        #pragma unroll
        for (int r = 0; r < 4; ++r) {
            float aA = qA[r] * gg, cA = bb - sA[r] * aA;
            float yA = silu_f(accA[nt][r] * aA + cA);
            accA[nt][r] = yA;
            dA[(oct * 16 + quad * 4 + r) * 8 + j] = f2bf(yA);
            float aB = qB[r] * gg, cB = bb - sB[r] * aB;
            float yB = silu_f(accB[nt][r] * aB + cB);
            accB[nt][r] = yB;
            dB[(oct * 16 + quad * 4 + r) * 8 + j] = f2bf(yB);
        }
    }
}

// -------------------- edge kernel: 1 wave, 32 edges (2 M-tiles), barrier-free ------
__global__ __launch_bounds__(64, 3) void edge_kernel(
    const unsigned short* __restrict__ hb, const int* __restrict__ ei,
    const float* __restrict__ coord, const float* __restrict__ eattr,
    const unsigned short* __restrict__ eW1f, const float* __restrict__ eW1,
    const float* __restrict__ eb1, const float* __restrict__ eg1, const float* __restrict__ ebe1,
    const unsigned short* __restrict__ eW2f,
    const float* __restrict__ eb2, const float* __restrict__ eg2, const float* __restrict__ ebe2,
    const unsigned short* __restrict__ cW1f,
    const float* __restrict__ cb1, const float* __restrict__ cg1, const float* __restrict__ cbe1,
    const float* __restrict__ cW2,
    float* __restrict__ agg, float* __restrict__ coord_out, int E)
{
    __shared__ unsigned short A2[2][2048];   // 4 KB per tile (C->A transpose buffer)

    const int lane = threadIdx.x;
    const int l15 = lane & 15, quad = lane >> 4;
    const int ge0 = blockIdx.x * 32;

    // per-lane edge (lane&31): indices + geometry
    int el = ge0 + (lane & 31);
    int elc = (el < E) ? el : (E - 1);
    int rowl = ei[elc], coll = ei[E + elc];
    float dx = coord[rowl * 3 + 0] - coord[coll * 3 + 0];
    float dy = coord[rowl * 3 + 1] - coord[coll * 3 + 1];
    float dz = coord[rowl * 3 + 2] - coord[coll * 3 + 2];
    float radial = dx * dx + dy * dy + dz * dz;
    float inv = 1.0f / (sqrtf(radial + 1e-8f) + 1.0f);
    float cdx = dx * inv, cdy = dy * inv, cdz = dz * inv;
    float ea = eattr[elc];

    // fragment-row indices for the two tiles
    int row_t0 = __shfl(rowl, l15, 64),      col_t0 = __shfl(coll, l15, 64);
    int row_t1 = __shfl(rowl, l15 + 16, 64), col_t1 = __shfl(coll, l15 + 16, 64);

    f32x4 accA[8], accB[8];
    #pragma unroll
    for (int nt = 0; nt < 8; ++nt) {
        accA[nt] = (f32x4){0.f, 0.f, 0.f, 0.f};
        accB[nt] = (f32x4){0.f, 0.f, 0.f, 0.f};
    }

    // ---- GEMM1: [32x256] @ eW1f, A direct from global ----
    for (int kb = 0; kb < 8; ++kb) {
        int ko = (kb & 3) * 32 + quad * 8;
        bf16x8 afA = *(const bf16x8*)(hb + (size_t)((kb < 4) ? row_t0 : col_t0) * H + ko);
        bf16x8 afB = *(const bf16x8*)(hb + (size_t)((kb < 4) ? row_t1 : col_t1) * H + ko);
        const unsigned short* bp = eW1f + ((size_t)kb * 8) * 512 + (size_t)lane * 8;
        #pragma unroll
        for (int nt = 0; nt < 8; ++nt) {
            bf16x8 bf = *(const bf16x8*)(bp + (size_t)nt * 512);
            accA[nt] = __builtin_amdgcn_mfma_f32_16x16x32_bf16(afA, bf, accA[nt], 0, 0, 0);
            accB[nt] = __builtin_amdgcn_mfma_f32_16x16x32_bf16(afB, bf, accB[nt], 0, 0, 0);
        }
    }

    // ---- rank-1 fp32 update: k=256 (radial), k=257 (eattr) ----
    {
        float radA[4], eaA[4], radB[4], eaB[4];
        #pragma unroll
        for (int r = 0; r < 4; ++r) {
            radA[r] = __shfl(radial, quad * 4 + r, 64);
            eaA[r]  = __shfl(ea,     quad * 4 + r, 64);
            radB[r] = __shfl(radial, 16 + quad * 4 + r, 64);
            eaB[r]  = __shfl(ea,     16 + quad * 4 + r, 64);
        }
        #pragma unroll
        for (int nt = 0; nt < 8; ++nt) {
            float w256 = eW1[256 * H + nt * 16 + l15];
            float w257 = eW1[257 * H + nt * 16 + l15];
            #pragma unroll
            for (int r = 0; r < 4; ++r) {
                accA[nt][r] += radA[r] * w256 + eaA[r] * w257;
                accB[nt][r] += radB[r] * w256 + eaB[r] * w257;
            }
        }
    }

    // ---- epilogue 1 (both tiles) -> A2 ----
    ln_silu_store2(accA, accB, eb1, eg1, ebe1, &A2[0][0], &A2[1][0], l15, quad);

    // ---- GEMM2: @ eW2f ----
    f32x4 ac2A[8], ac2B[8];
    #pragma unroll
    for (int nt = 0; nt < 8; ++nt) {
        ac2A[nt] = (f32x4){0.f, 0.f, 0.f, 0.f};
        ac2B[nt] = (f32x4){0.f, 0.f, 0.f, 0.f};
    }
    for (int kb = 0; kb < 4; ++kb) {
        bf16x8 afA = *(const bf16x8*)&A2[0][((kb * 4 + quad) * 16 + l15) * 8];
        bf16x8 afB = *(const bf16x8*)&A2[1][((kb * 4 + quad) * 16 + l15) * 8];
        const unsigned short* bp = eW2f + ((size_t)kb * 8) * 512 + (size_t)lane * 8;
        #pragma unroll
        for (int nt = 0; nt < 8; ++nt) {
            bf16x8 bf = *(const bf16x8*)(bp + (size_t)nt * 512);
            ac2A[nt] = __builtin_amdgcn_mfma_f32_16x16x32_bf16(afA, bf, ac2A[nt], 0, 0, 0);
            ac2B[nt] = __builtin_amdgcn_mfma_f32_16x16x32_bf16(afB, bf, ac2B[nt], 0, 0, 0);
        }
    }

    // ---- epilogue 2 = edge_feat -> A2 (aliased); agg atomics ----
    ln_silu_store2(ac2A, ac2B, eb2, eg2, ebe2, &A2[0][0], &A2[1][0], l15, quad);

    {
        int rowA[4], rowB[4];
        #pragma unroll
        for (int r = 0; r < 4; ++r) {
            rowA[r] = __shfl(rowl, quad * 4 + r, 64);
            rowB[r] = __shfl(rowl, 16 + quad * 4 + r, 64);
        }
        #pragma unroll
        for (int nt = 0; nt < 8; ++nt) {
            #pragma unroll
            for (int r = 0; r < 4; ++r) {
                int geA = ge0 + quad * 4 + r;
                int geB = geA + 16;
                if (geA < E) atomicAdd(&agg[(size_t)rowA[r] * H + nt * 16 + l15], ac2A[nt][r]);
                if (geB < E) atomicAdd(&agg[(size_t)rowB[r] * H + nt * 16 + l15], ac2B[nt][r]);
            }
        }
    }

    // ---- GEMM3: edge_feat @ cW1f ----
    #pragma unroll
    for (int nt = 0; nt < 8; ++nt) {
        accA[nt] = (f32x4){0.f, 0.f, 0.f, 0.f};
        accB[nt] = (f32x4){0.f, 0.f, 0.f, 0.f};
    }
    for (int kb = 0; kb < 4; ++kb) {
        bf16x8 afA = *(const bf16x8*)&A2[0][((kb * 4 + quad) * 16 + l15) * 8];
        bf16x8 afB = *(const bf16x8*)&A2[1][((kb * 4 + quad) * 16 + l15) * 8];
        const unsigned short* bp = cW1f + ((size_t)kb * 8) * 512 + (size_t)lane * 8;
        #pragma unroll
        for (int nt = 0; nt < 8; ++nt) {
            bf16x8 bf = *(const bf16x8*)(bp + (size_t)nt * 512);
            accA[nt] = __builtin_amdgcn_mfma_f32_16x16x32_bf16(afA, bf, accA[nt], 0, 0, 0);
            accB[nt] = __builtin_amdgcn_mfma_f32_16x16x32_bf16(afB, bf, accB[nt], 0, 0, 0);
        }
    }

    // ---- epilogue 3 (both tiles interleaved): LN + SiLU, dot cW2 -> cm; coord atomics ----
    {
        float sA[4] = {0,0,0,0}, qA[4] = {0,0,0,0};
        float sB[4] = {0,0,0,0}, qB[4] = {0,0,0,0};
        #pragma unroll
        for (int nt = 0; nt < 8; ++nt) {
            float b = cb1[nt * 16 + l15];
            #pragma unroll
            for (int r = 0; r < 4; ++r) {
                float xA = accA[nt][r] + b; accA[nt][r] = xA; sA[r] += xA; qA[r] += xA * xA;
                float xB = accB[nt][r] + b; accB[nt][r] = xB; sB[r] += xB; qB[r] += xB * xB;
            }
        }
        #pragma unroll
        for (int m = 1; m <= 8; m <<= 1) {
            #pragma unroll
            for (int r = 0; r < 4; ++r) {
                sA[r] += __shfl_xor(sA[r], m, 64); qA[r] += __shfl_xor(qA[r], m, 64);
                sB[r] += __shfl_xor(sB[r], m, 64); qB[r] += __shfl_xor(qB[r], m, 64);
            }
        }
        #pragma unroll
        for (int r = 0; r < 4; ++r) {
            float muA = sA[r] * 0.0078125f, vA = qA[r] * 0.0078125f - muA * muA;
            sA[r] = muA; qA[r] = rsqrtf(vA + 1e-5f);
            float muB = sB[r] * 0.0078125f, vB = qB[r] * 0.0078125f - muB * muB;
            sB[r] = muB; qB[r] = rsqrtf(vB + 1e-5f);
        }
        float cmA[4] = {0,0,0,0}, cmB[4] = {0,0,0,0};
        #pragma unroll
        for (int nt = 0; nt < 8; ++nt) {
            float gg = cg1[nt * 16 + l15], bb = cbe1[nt * 16 + l15];
            float w2 = cW2[nt * 16 + l15];
            #pragma unroll
            for (int r = 0; r < 4; ++r) {
                float aA = qA[r] * gg, cA = bb - sA[r] * aA;
                cmA[r] += silu_f(accA[nt][r] * aA + cA) * w2;
                float aB = qB[r] * gg, cB = bb - sB[r] * aB;
                cmB[r] += silu_f(accB[nt][r] * aB + cB) * w2;
            }
        }
        #pragma unroll
        for (int m = 1; m <= 8; m <<= 1) {
            #pragma unroll
            for (int r = 0; r < 4; ++r) {
                cmA[r] += __shfl_xor(cmA[r], m, 64);
                cmB[r] += __shfl_xor(cmB[r], m, 64);
            }
        }
        #pragma unroll
        for (int tile = 0; tile < 2; ++tile) {
            float* cm = tile ? cmB : cmA;
            #pragma unroll
            for (int r = 0; r < 4; ++r) {
                int src = tile * 16 + quad * 4 + r;
                float cdxr = __shfl(cdx, src, 64);
                float cdyr = __shfl(cdy, src, 64);
                float cdzr = __shfl(cdz, src, 64);
                int rw = __shfl(rowl, src, 64);
                float comp = (l15 == 0) ? cdxr : ((l15 == 1) ? cdyr : cdzr);
                int geh = ge0 + src;
                if (l15 < 3 && geh < E)
                    atomicAdd(&coord_out[(size_t)rw * 3 + l15], comp * cm[r]);
            }
        }
    }
}

// -------------------- node kernel: 1 wave, 32 nodes (2 M-tiles) --------------------
__global__ __launch_bounds__(64, 3) void node_kernel(
    const unsigned short* __restrict__ hb, const float* __restrict__ h,
    const float* __restrict__ agg,
    const unsigned short* __restrict__ nW1f,
    const float* __restrict__ nb1, const float* __restrict__ ng1, const float* __restrict__ nbe1,
    const unsigned short* __restrict__ nW2f, const float* __restrict__ nb2,
    float* __restrict__ out, int N)
{
    __shared__ unsigned short A2[2][2048];

    const int lane = threadIdx.x;
    const int l15 = lane & 15, quad = lane >> 4;
    const int gn0 = blockIdx.x * 32;

    int n_t0 = gn0 + l15;      if (n_t0 >= N) n_t0 = N - 1;
    int n_t1 = gn0 + 16 + l15; if (n_t1 >= N) n_t1 = N - 1;

    f32x4 accA[8], accB[8];
    #pragma unroll
    for (int nt = 0; nt < 8; ++nt) {
        accA[nt] = (f32x4){0.f, 0.f, 0.f, 0.f};
        accB[nt] = (f32x4){0.f, 0.f, 0.f, 0.f};
    }

    // ---- GEMM1: [32x256] @ nW1f; k<128 from hb (bf16), k>=128 from agg (fp32, cvt) ----
    for (int kb = 0; kb < 8; ++kb) {
        int ko = (kb & 3) * 32 + quad * 8;
        bf16x8 afA, afB;
        if (kb < 4) {
            afA = *(const bf16x8*)(hb + (size_t)n_t0 * H + ko);
            afB = *(const bf16x8*)(hb + (size_t)n_t1 * H + ko);
        } else {
            afA = ld_cvt8(agg + (size_t)n_t0 * H + ko);
            afB = ld_cvt8(agg + (size_t)n_t1 * H + ko);
        }
        const unsigned short* bp = nW1f + ((size_t)kb * 8) * 512 + (size_t)lane * 8;
        #pragma unroll
        for (int nt = 0; nt < 8; ++nt) {
            bf16x8 bf = *(const bf16x8*)(bp + (size_t)nt * 512);
            accA[nt] = __builtin_amdgcn_mfma_f32_16x16x32_bf16(afA, bf, accA[nt], 0, 0, 0);
            accB[nt] = __builtin_amdgcn_mfma_f32_16x16x32_bf16(afB, bf, accB[nt], 0, 0, 0);
        }
    }

    ln_silu_store2(accA, accB, nb1, ng1, nbe1, &A2[0][0], &A2[1][0], l15, quad);

    // ---- GEMM2: @ nW2f ----
    f32x4 ac2A[8], ac2B[8];
    #pragma unroll
    for (int nt = 0; nt < 8; ++nt) {
        ac2A[nt] = (f32x4){0.f, 0.f, 0.f, 0.f};
        ac2B[nt] = (f32x4){0.f, 0.f, 0.f, 0.f};
    }
    for (int kb = 0; kb < 4; ++kb) {
        bf16x8 afA = *(const bf16x8*)&A2[0][((kb * 4 + quad) * 16 + l15) * 8];
        bf16x8 afB = *(const bf16x8*)&A2[1][((kb * 4 + quad) * 16 + l15) * 8];
        const unsigned short* bp = nW2f + ((size_t)kb * 8) * 512 + (size_t)lane * 8;
        #pragma unroll
        for (int nt = 0; nt < 8; ++nt) {
            bf16x8 bf = *(const bf16x8*)(bp + (size_t)nt * 512);
            ac2A[nt] = __builtin_amdgcn_mfma_f32_16x16x32_bf16(afA, bf, ac2A[nt], 0, 0, 0);
            ac2B[nt] = __builtin_amdgcn_mfma_f32_16x16x32_bf16(afB, bf, ac2B[nt], 0, 0, 0);
        }
    }

    // ---- out = h + acc2 + b ----
    #pragma unroll
    for (int nt = 0; nt < 8; ++nt) {
        float b = nb2[nt * 16 + l15];
        #pragma unroll
        for (int r = 0; r < 4; ++r) {
            int gA = gn0 + quad * 4 + r;
            int gB = gA + 16;
            if (gA < N) {
                size_t idx = (size_t)gA * H + nt * 16 + l15;
                out[idx] = ac2A[nt][r] + b + h[idx];
            }
            if (gB < N) {
                size_t idx = (size_t)gB * H + nt * 16 + l15;
                out[idx] = ac2B[nt][r] + b + h[idx];
            }
        }
    }
}

// -------------------- launch --------------------
extern "C" void kernel_launch(void* const* d_in, const int* in_sizes, int n_in,
                              void* d_out, int out_size, void* d_ws, size_t ws_size,
                              hipStream_t stream) {
    const float* h     = (const float*)d_in[0];
    const int*   ei    = (const int*)d_in[1];
    const float* coord = (const float*)d_in[2];
    const float* eattr = (const float*)d_in[3];
    const float* eW1   = (const float*)d_in[4];
    const float* eb1   = (const float*)d_in[5];
    const float* eg1   = (const float*)d_in[6];
    const float* ebe1  = (const float*)d_in[7];
    const float* eW2   = (const float*)d_in[8];
    const float* eb2   = (const float*)d_in[9];
    const float* eg2   = (const float*)d_in[10];
    const float* ebe2  = (const float*)d_in[11];
    const float* nW1   = (const float*)d_in[12];
    const float* nb1   = (const float*)d_in[13];
    const float* ng1   = (const float*)d_in[14];
    const float* nbe1  = (const float*)d_in[15];
    const float* nW2   = (const float*)d_in[16];
    const float* nb2   = (const float*)d_in[17];
    const float* cW1   = (const float*)d_in[18];
    const float* cb1   = (const float*)d_in[19];
    const float* cg1   = (const float*)d_in[20];
    const float* cbe1  = (const float*)d_in[21];
    const float* cW2   = (const float*)d_in[22];

    const int N = in_sizes[0] / H;
    const int E = in_sizes[1] / 2;

    float* out       = (float*)d_out;
    float* coord_out = out + (size_t)N * H;

    // ---- workspace layout ----
    char* ws = (char*)d_ws;
    size_t o = 0;
    float* agg = (float*)(ws + o);                    o += (size_t)N * H * 4;
    unsigned short* hb   = (unsigned short*)(ws + o); o += (size_t)N * H * 2;
    unsigned short* eW1f = (unsigned short*)(ws + o); o += (size_t)H * KE * 2;
    unsigned short* eW2f = (unsigned short*)(ws + o); o += (size_t)H * H * 2;
    unsigned short* cW1f = (unsigned short*)(ws + o); o += (size_t)H * H * 2;
    unsigned short* nW1f = (unsigned short*)(ws + o); o += (size_t)H * KN * 2;
    unsigned short* nW2f = (unsigned short*)(ws + o); o += (size_t)H * H * 2;

    hipMemsetAsync(agg, 0, (size_t)N * H * sizeof(float), stream);
    hipMemcpyAsync(coord_out, coord, (size_t)N * 3 * sizeof(float),
                   hipMemcpyDeviceToDevice, stream);

    prep_h<<<(N * H / 4 + 255) / 256, 256, 0, stream>>>(h, hb, N * H / 4);
    prep_w_all<<<dim3(64, 5), 64, 0, stream>>>(eW1, eW2, cW1, nW1, nW2,
                                               eW1f, eW2f, cW1f, nW1f, nW2f);

    edge_kernel<<<(E + 31) / 32, 64, 0, stream>>>(
        hb, ei, coord, eattr,
        eW1f, eW1, eb1, eg1, ebe1,
        eW2f, eb2, eg2, ebe2,
        cW1f, cb1, cg1, cbe1, cW2,
        agg, coord_out, E);

    node_kernel<<<(N + 31) / 32, 64, 0, stream>>>(
        hb, h, agg, nW1f, nb1, ng1, nbe1, nW2f, nb2, out, N);
}

// Round 7
// 410.019 us; speedup vs baseline: 1.1038x; 1.1038x over previous
//
#include <hip/hip_runtime.h>
#include <math.h>

#define H 128
#define KE 256      // MFMA K for edge GEMM1 (k=256,257 via fp32 rank-1 update)
#define KN 256      // node GEMM1 K (2H)
#define XSTR 136    // LDS transpose-buffer row stride (elems): 16B-aligned rows, 4-way max bank conflict

typedef __attribute__((ext_vector_type(8))) short bf16x8;
typedef __attribute__((ext_vector_type(4))) float f32x4;

__device__ __forceinline__ float silu_f(float x) { return x / (1.0f + __expf(-x)); }

__device__ __forceinline__ unsigned short f2bf(float f) {
    unsigned int u = __float_as_uint(f);
    unsigned int r = u + 0x7FFFu + ((u >> 16) & 1u);
    return (unsigned short)(r >> 16);
}

// load 8 consecutive fp32, convert to bf16x8 fragment
__device__ __forceinline__ bf16x8 ld_cvt8(const float* p) {
    float4 f0 = ((const float4*)p)[0];
    float4 f1 = ((const float4*)p)[1];
    union { bf16x8 v; unsigned short u[8]; } pk;
    pk.u[0] = f2bf(f0.x); pk.u[1] = f2bf(f0.y); pk.u[2] = f2bf(f0.z); pk.u[3] = f2bf(f0.w);
    pk.u[4] = f2bf(f1.x); pk.u[5] = f2bf(f1.y); pk.u[6] = f2bf(f1.z); pk.u[7] = f2bf(f1.w);
    return pk.v;
}

// -------------------- prep: h fp32 -> bf16 (vectorized x4) --------------------
__global__ void prep_h(const float* __restrict__ x, unsigned short* __restrict__ y, int n4) {
    int i = blockIdx.x * 256 + threadIdx.x;
    if (i < n4) {
        float4 f = ((const float4*)x)[i];
        ushort4 o;
        o.x = f2bf(f.x); o.y = f2bf(f.y); o.z = f2bf(f.z); o.w = f2bf(f.w);
        ((ushort4*)y)[i] = o;
    }
}

// ---- prep all weights: W[K][128] fp32 -> fragment-linear Wf[(kb*8+nt)*64+lane][8] ----
__global__ void prep_w_all(
    const float* __restrict__ eW1, const float* __restrict__ eW2,
    const float* __restrict__ cW1, const float* __restrict__ nW1,
    const float* __restrict__ nW2,
    unsigned short* __restrict__ eW1f, unsigned short* __restrict__ eW2f,
    unsigned short* __restrict__ cW1f, unsigned short* __restrict__ nW1f,
    unsigned short* __restrict__ nW2f)
{
    const float* W; unsigned short* Wf; int nfrag;
    switch (blockIdx.y) {
        case 0:  W = eW1; Wf = eW1f; nfrag = 8 * 8 * 64; break;
        case 1:  W = eW2; Wf = eW2f; nfrag = 4 * 8 * 64; break;
        case 2:  W = cW1; Wf = cW1f; nfrag = 4 * 8 * 64; break;
        case 3:  W = nW1; Wf = nW1f; nfrag = 8 * 8 * 64; break;
        default: W = nW2; Wf = nW2f; nfrag = 4 * 8 * 64; break;
    }
    int f = blockIdx.x * 64 + threadIdx.x;
    if (f >= nfrag) return;
    int kb = f >> 9;
    int rem = f & 511;
    int nt = rem >> 6, lane = rem & 63;
    int quad = lane >> 4, l15 = lane & 15;
    int n = nt * 16 + l15, k0 = kb * 32 + quad * 8;
    union { bf16x8 v; unsigned short u[8]; } pk;
    #pragma unroll
    for (int j = 0; j < 8; ++j) pk.u[j] = f2bf(W[(size_t)(k0 + j) * H + n]);
    *(bf16x8*)&Wf[(size_t)f * 8] = pk.v;
}

// ---- single-tile epilogue: bias + LN + SiLU; result left in acc, bf16 copy in LDS ----
// LDS layout: X[row][col], row stride XSTR elems (row = edge-in-tile, col = feature)
__device__ __forceinline__ void ln_silu_store1(
    f32x4* acc, const float* __restrict__ bias, const float* __restrict__ g,
    const float* __restrict__ be, unsigned short* X, int l15, int quad)
{
    float s[4] = {0,0,0,0}, q[4] = {0,0,0,0};
    #pragma unroll
    for (int nt = 0; nt < 8; ++nt) {
        float b = bias[nt * 16 + l15];
        #pragma unroll
        for (int r = 0; r < 4; ++r) {
            float x = acc[nt][r] + b; acc[nt][r] = x; s[r] += x; q[r] += x * x;
        }
    }
    #pragma unroll
    for (int m = 1; m <= 8; m <<= 1) {
        #pragma unroll
        for (int r = 0; r < 4; ++r) {
            s[r] += __shfl_xor(s[r], m, 64); q[r] += __shfl_xor(q[r], m, 64);
        }
    }
    #pragma unroll
    for (int r = 0; r < 4; ++r) {
        float mu = s[r] * 0.0078125f, v = q[r] * 0.0078125f - mu * mu;
        s[r] = mu; q[r] = rsqrtf(v + 1e-5f);
    }
    #pragma unroll
    for (int nt = 0; nt < 8; ++nt) {
        float gg = g[nt * 16 + l15], bb = be[nt * 16 + l15];
        #pragma unroll
        for (int r = 0; r < 4; ++r) {
            float a = q[r] * gg, c = bb - s[r] * a;
            float y = silu_f(acc[nt][r] * a + c);
            acc[nt][r] = y;
            X[(quad * 4 + r) * XSTR + nt * 16 + l15] = f2bf(y);
        }
    }
}

// -------------------- edge kernel: 1 wave, 16 edges, barrier-free --------------------
__global__ __launch_bounds__(64, 4) void edge_kernel(
    const unsigned short* __restrict__ hb, const int* __restrict__ ei,
    const float* __restrict__ coord, const float* __restrict__ eattr,
    const unsigned short* __restrict__ eW1f, const float* __restrict__ eW1,
    const float* __restrict__ eb1, const float* __restrict__ eg1, const float* __restrict__ ebe1,
    const unsigned short* __restrict__ eW2f,
    const float* __restrict__ eb2, const float* __restrict__ eg2, const float* __restrict__ ebe2,
    const unsigned short* __restrict__ cW1f,
    const float* __restrict__ cb1, const float* __restrict__ cg1, const float* __restrict__ cbe1,
    const float* __restrict__ cW2,
    float* __restrict__ agg, float* __restrict__ coord_out, int E)
{
    __shared__ unsigned short X[16 * XSTR];   // 4352 B transpose buffer

    const int lane = threadIdx.x;
    const int l15 = lane & 15, quad = lane >> 4;
    const int ge0 = blockIdx.x * 16;

    // each lane handles edge ge0+l15 (duplicated across quads; no shuffles for A addressing)
    int el  = ge0 + l15;
    int elc = (el < E) ? el : (E - 1);
    int rowl = ei[elc], coll = ei[E + elc];
    float dx = coord[rowl * 3 + 0] - coord[coll * 3 + 0];
    float dy = coord[rowl * 3 + 1] - coord[coll * 3 + 1];
    float dz = coord[rowl * 3 + 2] - coord[coll * 3 + 2];
    float radial = dx * dx + dy * dy + dz * dz;
    float inv = 1.0f / (sqrtf(radial + 1e-8f) + 1.0f);
    float cdx = dx * inv, cdy = dy * inv, cdz = dz * inv;
    float ea = eattr[elc];

    f32x4 acc[8];
    #pragma unroll
    for (int nt = 0; nt < 8; ++nt) acc[nt] = (f32x4){0.f, 0.f, 0.f, 0.f};

    // ---- GEMM1: [16x256] @ eW1f, A direct from global (hb rows l15-mapped) ----
    for (int kb = 0; kb < 8; ++kb) {
        int ko = (kb & 3) * 32 + quad * 8;
        bf16x8 af = *(const bf16x8*)(hb + (size_t)((kb < 4) ? rowl : coll) * H + ko);
        const unsigned short* bp = eW1f + ((size_t)kb * 8) * 512 + (size_t)lane * 8;
        #pragma unroll
        for (int nt = 0; nt < 8; ++nt) {
            bf16x8 bf = *(const bf16x8*)(bp + (size_t)nt * 512);
            acc[nt] = __builtin_amdgcn_mfma_f32_16x16x32_bf16(af, bf, acc[nt], 0, 0, 0);
        }
    }

    // ---- rank-1 fp32 update: k=256 (radial), k=257 (eattr) ----
    {
        float rad_r[4], ea_r[4];
        #pragma unroll
        for (int r = 0; r < 4; ++r) {
            rad_r[r] = __shfl(radial, quad * 4 + r, 64);
            ea_r[r]  = __shfl(ea,     quad * 4 + r, 64);
        }
        #pragma unroll
        for (int nt = 0; nt < 8; ++nt) {
            float w256 = eW1[256 * H + nt * 16 + l15];
            float w257 = eW1[257 * H + nt * 16 + l15];
            #pragma unroll
            for (int r = 0; r < 4; ++r)
                acc[nt][r] += rad_r[r] * w256 + ea_r[r] * w257;
        }
    }

    // ---- epilogue 1 -> X ----
    ln_silu_store1(acc, eb1, eg1, ebe1, X, l15, quad);

    // ---- GEMM2: [16x128] @ eW2f ----
    f32x4 ac2[8];
    #pragma unroll
    for (int nt = 0; nt < 8; ++nt) ac2[nt] = (f32x4){0.f, 0.f, 0.f, 0.f};
    for (int kb = 0; kb < 4; ++kb) {
        bf16x8 af = *(const bf16x8*)&X[l15 * XSTR + kb * 32 + quad * 8];
        const unsigned short* bp = eW2f + ((size_t)kb * 8) * 512 + (size_t)lane * 8;
        #pragma unroll
        for (int nt = 0; nt < 8; ++nt) {
            bf16x8 bf = *(const bf16x8*)(bp + (size_t)nt * 512);
            ac2[nt] = __builtin_amdgcn_mfma_f32_16x16x32_bf16(af, bf, ac2[nt], 0, 0, 0);
        }
    }

    // ---- epilogue 2 = edge_feat -> X (safe: same-wave LDS ops are in-order); agg atomics ----
    ln_silu_store1(ac2, eb2, eg2, ebe2, X, l15, quad);

    {
        int rowm[4];
        #pragma unroll
        for (int r = 0; r < 4; ++r) rowm[r] = __shfl(rowl, quad * 4 + r, 64);
        #pragma unroll
        for (int nt = 0; nt < 8; ++nt) {
            #pragma unroll
            for (int r = 0; r < 4; ++r) {
                int geh = ge0 + quad * 4 + r;
                if (geh < E)
                    atomicAdd(&agg[(size_t)rowm[r] * H + nt * 16 + l15], ac2[nt][r]);
            }
        }
    }

    // ---- GEMM3: edge_feat @ cW1f ----
    #pragma unroll
    for (int nt = 0; nt < 8; ++nt) acc[nt] = (f32x4){0.f, 0.f, 0.f, 0.f};
    for (int kb = 0; kb < 4; ++kb) {
        bf16x8 af = *(const bf16x8*)&X[l15 * XSTR + kb * 32 + quad * 8];
        const unsigned short* bp = cW1f + ((size_t)kb * 8) * 512 + (size_t)lane * 8;
        #pragma unroll
        for (int nt = 0; nt < 8; ++nt) {
            bf16x8 bf = *(const bf16x8*)(bp + (size_t)nt * 512);
            acc[nt] = __builtin_amdgcn_mfma_f32_16x16x32_bf16(af, bf, acc[nt], 0, 0, 0);
        }
    }

    // ---- epilogue 3: bias + LN + SiLU, dot cW2 -> cm; coord atomics ----
    {
        float s[4] = {0,0,0,0}, q[4] = {0,0,0,0};
        #pragma unroll
        for (int nt = 0; nt < 8; ++nt) {
            float b = cb1[nt * 16 + l15];
            #pragma unroll
            for (int r = 0; r < 4; ++r) {
                float x = acc[nt][r] + b; acc[nt][r] = x; s[r] += x; q[r] += x * x;
            }
        }
        #pragma unroll
        for (int m = 1; m <= 8; m <<= 1) {
            #pragma unroll
            for (int r = 0; r < 4; ++r) {
                s[r] += __shfl_xor(s[r], m, 64); q[r] += __shfl_xor(q[r], m, 64);
            }
        }
        #pragma unroll
        for (int r = 0; r < 4; ++r) {
            float mu = s[r] * 0.0078125f, v = q[r] * 0.0078125f - mu * mu;
            s[r] = mu; q[r] = rsqrtf(v + 1e-5f);
        }
        float cm[4] = {0,0,0,0};
        #pragma unroll
        for (int nt = 0; nt < 8; ++nt) {
            float gg = cg1[nt * 16 + l15], bb = cbe1[nt * 16 + l15];
            float w2 = cW2[nt * 16 + l15];
            #pragma unroll
            for (int r = 0; r < 4; ++r) {
                float a = q[r] * gg, c = bb - s[r] * a;
                cm[r] += silu_f(acc[nt][r] * a + c) * w2;
            }
        }
        #pragma unroll
        for (int m = 1; m <= 8; m <<= 1) {
            #pragma unroll
            for (int r = 0; r < 4; ++r) cm[r] += __shfl_xor(cm[r], m, 64);
        }
        #pragma unroll
        for (int r = 0; r < 4; ++r) {
            int src = quad * 4 + r;
            float cdxr = __shfl(cdx, src, 64);
            float cdyr = __shfl(cdy, src, 64);
            float cdzr = __shfl(cdz, src, 64);
            int rw = __shfl(rowl, src, 64);
            float comp = (l15 == 0) ? cdxr : ((l15 == 1) ? cdyr : cdzr);
            int geh = ge0 + src;
            if (l15 < 3 && geh < E)
                atomicAdd(&coord_out[(size_t)rw * 3 + l15], comp * cm[r]);
        }
    }
}

// ---- dual-tile epilogue for node kernel (unchanged from R5 layout) ----
__device__ __forceinline__ void ln_silu_store2(
    f32x4* accA, f32x4* accB,
    const float* __restrict__ bias, const float* __restrict__ g,
    const float* __restrict__ be,
    unsigned short* dA, unsigned short* dB, int l15, int quad)
{
    float sA[4] = {0,0,0,0}, qA[4] = {0,0,0,0};
    float sB[4] = {0,0,0,0}, qB[4] = {0,0,0,0};
    #pragma unroll
    for (int nt = 0; nt < 8; ++nt) {
        float b = bias[nt * 16 + l15];
        #pragma unroll
        for (int r = 0; r < 4; ++r) {
            float xA = accA[nt][r] + b; accA[nt][r] = xA; sA[r] += xA; qA[r] += xA * xA;
            float xB = accB[nt][r] + b; accB[nt][r] = xB; sB[r] += xB; qB[r] += xB * xB;
        }
    }
    #pragma unroll
    for (int m = 1; m <= 8; m <<= 1) {
        #pragma unroll
        for (int r = 0; r < 4; ++r) {
            sA[r] += __shfl_xor(sA[r], m, 64); qA[r] += __shfl_xor(qA[r], m, 64);
            sB[r] += __shfl_xor(sB[r], m, 64); qB[r] += __shfl_xor(qB[r], m, 64);
        }
    }
    #pragma unroll
    for (int r = 0; r < 4; ++r) {
        float muA = sA[r] * 0.0078125f, vA = qA[r] * 0.0078125f - muA * muA;
        sA[r] = muA; qA[r] = rsqrtf(vA + 1e-5f);
        float muB = sB[r] * 0.0078125f, vB = qB[r] * 0.0078125f - muB * muB;
        sB[r] = muB; qB[r] = rsqrtf(vB + 1e-5f);
    }
    #pragma unroll
    for (int nt = 0; nt < 8; ++nt) {
        float gg = g[nt * 16 + l15], bb = be[nt * 16 + l15];
        #pragma unroll
        for (int r = 0; r < 4; ++r) {
            float aA = qA[r] * gg, cA = bb - sA[r] * aA;
            float yA = silu_f(accA[nt][r] * aA + cA);
            accA[nt][r] = yA;
            dA[(quad * 4 + r) * XSTR + nt * 16 + l15] = f2bf(yA);
            float aB = qB[r] * gg, cB = bb - sB[r] * aB;
            float yB = silu_f(accB[nt][r] * aB + cB);
            accB[nt][r] = yB;
            dB[(quad * 4 + r) * XSTR + nt * 16 + l15] = f2bf(yB);
        }
    }
}

// -------------------- node kernel: 1 wave, 32 nodes (2 M-tiles) --------------------
__global__ __launch_bounds__(64) void node_kernel(
    const unsigned short* __restrict__ hb, const float* __restrict__ h,
    const float* __restrict__ agg,
    const unsigned short* __restrict__ nW1f,
    const float* __restrict__ nb1, const float* __restrict__ ng1, const float* __restrict__ nbe1,
    const unsigned short* __restrict__ nW2f, const float* __restrict__ nb2,
    float* __restrict__ out, int N)
{
    __shared__ unsigned short X2[2][16 * XSTR];

    const int lane = threadIdx.x;
    const int l15 = lane & 15, quad = lane >> 4;
    const int gn0 = blockIdx.x * 32;

    int n_t0 = gn0 + l15;      if (n_t0 >= N) n_t0 = N - 1;
    int n_t1 = gn0 + 16 + l15; if (n_t1 >= N) n_t1 = N - 1;

    f32x4 accA[8], accB[8];
    #pragma unroll
    for (int nt = 0; nt < 8; ++nt) {
        accA[nt] = (f32x4){0.f, 0.f, 0.f, 0.f};
        accB[nt] = (f32x4){0.f, 0.f, 0.f, 0.f};
    }

    // ---- GEMM1: [32x256] @ nW1f; k<128 from hb (bf16), k>=128 from agg (fp32, cvt) ----
    for (int kb = 0; kb < 8; ++kb) {
        int ko = (kb & 3) * 32 + quad * 8;
        bf16x8 afA, afB;
        if (kb < 4) {
            afA = *(const bf16x8*)(hb + (size_t)n_t0 * H + ko);
            afB = *(const bf16x8*)(hb + (size_t)n_t1 * H + ko);
        } else {
            afA = ld_cvt8(agg + (size_t)n_t0 * H + ko);
            afB = ld_cvt8(agg + (size_t)n_t1 * H + ko);
        }
        const unsigned short* bp = nW1f + ((size_t)kb * 8) * 512 + (size_t)lane * 8;
        #pragma unroll
        for (int nt = 0; nt < 8; ++nt) {
            bf16x8 bf = *(const bf16x8*)(bp + (size_t)nt * 512);
            accA[nt] = __builtin_amdgcn_mfma_f32_16x16x32_bf16(afA, bf, accA[nt], 0, 0, 0);
            accB[nt] = __builtin_amdgcn_mfma_f32_16x16x32_bf16(afB, bf, accB[nt], 0, 0, 0);
        }
    }

    ln_silu_store2(accA, accB, nb1, ng1, nbe1, &X2[0][0], &X2[1][0], l15, quad);

    // ---- GEMM2: @ nW2f ----
    f32x4 ac2A[8], ac2B[8];
    #pragma unroll
    for (int nt = 0; nt < 8; ++nt) {
        ac2A[nt] = (f32x4){0.f, 0.f, 0.f, 0.f};
        ac2B[nt] = (f32x4){0.f, 0.f, 0.f, 0.f};
    }
    for (int kb = 0; kb < 4; ++kb) {
        bf16x8 afA = *(const bf16x8*)&X2[0][l15 * XSTR + kb * 32 + quad * 8];
        bf16x8 afB = *(const bf16x8*)&X2[1][l15 * XSTR + kb * 32 + quad * 8];
        const unsigned short* bp = nW2f + ((size_t)kb * 8) * 512 + (size_t)lane * 8;
        #pragma unroll
        for (int nt = 0; nt < 8; ++nt) {
            bf16x8 bf = *(const bf16x8*)(bp + (size_t)nt * 512);
            ac2A[nt] = __builtin_amdgcn_mfma_f32_16x16x32_bf16(afA, bf, ac2A[nt], 0, 0, 0);
            ac2B[nt] = __builtin_amdgcn_mfma_f32_16x16x32_bf16(afB, bf, ac2B[nt], 0, 0, 0);
        }
    }

    // ---- out = h + acc2 + b ----
    #pragma unroll
    for (int nt = 0; nt < 8; ++nt) {
        float b = nb2[nt * 16 + l15];
        #pragma unroll
        for (int r = 0; r < 4; ++r) {
            int gA = gn0 + quad * 4 + r;
            int gB = gA + 16;
            if (gA < N) {
                size_t idx = (size_t)gA * H + nt * 16 + l15;
                out[idx] = ac2A[nt][r] + b + h[idx];
            }
            if (gB < N) {
                size_t idx = (size_t)gB * H + nt * 16 + l15;
                out[idx] = ac2B[nt][r] + b + h[idx];
            }
        }
    }
}

// -------------------- launch --------------------
extern "C" void kernel_launch(void* const* d_in, const int* in_sizes, int n_in,
                              void* d_out, int out_size, void* d_ws, size_t ws_size,
                              hipStream_t stream) {
    const float* h     = (const float*)d_in[0];
    const int*   ei    = (const int*)d_in[1];
    const float* coord = (const float*)d_in[2];
    const float* eattr = (const float*)d_in[3];
    const float* eW1   = (const float*)d_in[4];
    const float* eb1   = (const float*)d_in[5];
    const float* eg1   = (const float*)d_in[6];
    const float* ebe1  = (const float*)d_in[7];
    const float* eW2   = (const float*)d_in[8];
    const float* eb2   = (const float*)d_in[9];
    const float* eg2   = (const float*)d_in[10];
    const float* ebe2  = (const float*)d_in[11];
    const float* nW1   = (const float*)d_in[12];
    const float* nb1   = (const float*)d_in[13];
    const float* ng1   = (const float*)d_in[14];
    const float* nbe1  = (const float*)d_in[15];
    const float* nW2   = (const float*)d_in[16];
    const float* nb2   = (const float*)d_in[17];
    const float* cW1   = (const float*)d_in[18];
    const float* cb1   = (const float*)d_in[19];
    const float* cg1   = (const float*)d_in[20];
    const float* cbe1  = (const float*)d_in[21];
    const float* cW2   = (const float*)d_in[22];

    const int N = in_sizes[0] / H;
    const int E = in_sizes[1] / 2;

    float* out       = (float*)d_out;
    float* coord_out = out + (size_t)N * H;

    // ---- workspace layout ----
    char* ws = (char*)d_ws;
    size_t o = 0;
    float* agg = (float*)(ws + o);                    o += (size_t)N * H * 4;
    unsigned short* hb   = (unsigned short*)(ws + o); o += (size_t)N * H * 2;
    unsigned short* eW1f = (unsigned short*)(ws + o); o += (size_t)H * KE * 2;
    unsigned short* eW2f = (unsigned short*)(ws + o); o += (size_t)H * H * 2;
    unsigned short* cW1f = (unsigned short*)(ws + o); o += (size_t)H * H * 2;
    unsigned short* nW1f = (unsigned short*)(ws + o); o += (size_t)H * KN * 2;
    unsigned short* nW2f = (unsigned short*)(ws + o); o += (size_t)H * H * 2;

    hipMemsetAsync(agg, 0, (size_t)N * H * sizeof(float), stream);
    hipMemcpyAsync(coord_out, coord, (size_t)N * 3 * sizeof(float),
                   hipMemcpyDeviceToDevice, stream);

    prep_h<<<(N * H / 4 + 255) / 256, 256, 0, stream>>>(h, hb, N * H / 4);
    prep_w_all<<<dim3(64, 5), 64, 0, stream>>>(eW1, eW2, cW1, nW1, nW2,
                                               eW1f, eW2f, cW1f, nW1f, nW2f);

    edge_kernel<<<(E + 15) / 16, 64, 0, stream>>>(
        hb, ei, coord, eattr,
        eW1f, eW1, eb1, eg1, ebe1,
        eW2f, eb2, eg2, ebe2,
        cW1f, cb1, cg1, cbe1, cW2,
        agg, coord_out, E);

    node_kernel<<<(N + 31) / 32, 64, 0, stream>>>(
        hb, h, agg, nW1f, nb1, ng1, nbe1, nW2f, nb2, out, N);
}

// Round 8
// 397.561 us; speedup vs baseline: 1.1384x; 1.0313x over previous
//
#include <hip/hip_runtime.h>
#include <math.h>

#define H 128
#define KE 256      // MFMA K for edge GEMM1 (k=256,257 via fp32 rank-1 update)
#define KN 256      // node GEMM1 K (2H)
#define XSTR 136    // LDS transpose-buffer row stride (elems)

typedef __attribute__((ext_vector_type(8))) short bf16x8;
typedef __attribute__((ext_vector_type(4))) float f32x4;

__device__ __forceinline__ float silu_f(float x) { return x / (1.0f + __expf(-x)); }

__device__ __forceinline__ unsigned short f2bf(float f) {
    unsigned int u = __float_as_uint(f);
    unsigned int r = u + 0x7FFFu + ((u >> 16) & 1u);
    return (unsigned short)(r >> 16);
}

// load 8 consecutive fp32, convert to bf16x8 fragment
__device__ __forceinline__ bf16x8 ld_cvt8(const float* p) {
    float4 f0 = ((const float4*)p)[0];
    float4 f1 = ((const float4*)p)[1];
    union { bf16x8 v; unsigned short u[8]; } pk;
    pk.u[0] = f2bf(f0.x); pk.u[1] = f2bf(f0.y); pk.u[2] = f2bf(f0.z); pk.u[3] = f2bf(f0.w);
    pk.u[4] = f2bf(f1.x); pk.u[5] = f2bf(f1.y); pk.u[6] = f2bf(f1.z); pk.u[7] = f2bf(f1.w);
    return pk.v;
}

// -------------------- prep: h fp32 -> bf16 (vectorized x4) --------------------
__global__ void prep_h(const float* __restrict__ x, unsigned short* __restrict__ y, int n4) {
    int i = blockIdx.x * 256 + threadIdx.x;
    if (i < n4) {
        float4 f = ((const float4*)x)[i];
        ushort4 o;
        o.x = f2bf(f.x); o.y = f2bf(f.y); o.z = f2bf(f.z); o.w = f2bf(f.w);
        ((ushort4*)y)[i] = o;
    }
}

// ---- prep all weights: W[K][128] fp32 -> fragment-linear Wf[(kb*8+nt)*64+lane][8] ----
__global__ void prep_w_all(
    const float* __restrict__ eW1, const float* __restrict__ eW2,
    const float* __restrict__ cW1, const float* __restrict__ nW1,
    const float* __restrict__ nW2,
    unsigned short* __restrict__ eW1f, unsigned short* __restrict__ eW2f,
    unsigned short* __restrict__ cW1f, unsigned short* __restrict__ nW1f,
    unsigned short* __restrict__ nW2f)
{
    const float* W; unsigned short* Wf; int nfrag;
    switch (blockIdx.y) {
        case 0:  W = eW1; Wf = eW1f; nfrag = 8 * 8 * 64; break;
        case 1:  W = eW2; Wf = eW2f; nfrag = 4 * 8 * 64; break;
        case 2:  W = cW1; Wf = cW1f; nfrag = 4 * 8 * 64; break;
        case 3:  W = nW1; Wf = nW1f; nfrag = 8 * 8 * 64; break;
        default: W = nW2; Wf = nW2f; nfrag = 4 * 8 * 64; break;
    }
    int f = blockIdx.x * 64 + threadIdx.x;
    if (f >= nfrag) return;
    int kb = f >> 9;
    int rem = f & 511;
    int nt = rem >> 6, lane = rem & 63;
    int quad = lane >> 4, l15 = lane & 15;
    int n = nt * 16 + l15, k0 = kb * 32 + quad * 8;
    union { bf16x8 v; unsigned short u[8]; } pk;
    #pragma unroll
    for (int j = 0; j < 8; ++j) pk.u[j] = f2bf(W[(size_t)(k0 + j) * H + n]);
    *(bf16x8*)&Wf[(size_t)f * 8] = pk.v;
}

// ---- single-tile epilogue: bias + LN + SiLU; result left in acc, bf16 copy in LDS ----
__device__ __forceinline__ void ln_silu_store1(
    f32x4* acc, const float* __restrict__ bias, const float* __restrict__ g,
    const float* __restrict__ be, unsigned short* X, int l15, int quad)
{
    float s[4] = {0,0,0,0}, q[4] = {0,0,0,0};
    #pragma unroll
    for (int nt = 0; nt < 8; ++nt) {
        float b = bias[nt * 16 + l15];
        #pragma unroll
        for (int r = 0; r < 4; ++r) {
            float x = acc[nt][r] + b; acc[nt][r] = x; s[r] += x; q[r] += x * x;
        }
    }
    #pragma unroll
    for (int m = 1; m <= 8; m <<= 1) {
        #pragma unroll
        for (int r = 0; r < 4; ++r) {
            s[r] += __shfl_xor(s[r], m, 64); q[r] += __shfl_xor(q[r], m, 64);
        }
    }
    #pragma unroll
    for (int r = 0; r < 4; ++r) {
        float mu = s[r] * 0.0078125f, v = q[r] * 0.0078125f - mu * mu;
        s[r] = mu; q[r] = rsqrtf(v + 1e-5f);
    }
    #pragma unroll
    for (int nt = 0; nt < 8; ++nt) {
        float gg = g[nt * 16 + l15], bb = be[nt * 16 + l15];
        #pragma unroll
        for (int r = 0; r < 4; ++r) {
            float a = q[r] * gg, c = bb - s[r] * a;
            float y = silu_f(acc[nt][r] * a + c);
            acc[nt][r] = y;
            X[(quad * 4 + r) * XSTR + nt * 16 + l15] = f2bf(y);
        }
    }
}

// ---- edge kernel: 256 threads = 4 independent waves, 16 edges each, no barriers ----
__global__ __launch_bounds__(256, 4) void edge_kernel(
    const unsigned short* __restrict__ hb, const int* __restrict__ ei,
    const float* __restrict__ coord, const float* __restrict__ eattr,
    const unsigned short* __restrict__ eW1f, const float* __restrict__ eW1,
    const float* __restrict__ eb1, const float* __restrict__ eg1, const float* __restrict__ ebe1,
    const unsigned short* __restrict__ eW2f,
    const float* __restrict__ eb2, const float* __restrict__ eg2, const float* __restrict__ ebe2,
    const unsigned short* __restrict__ cW1f,
    const float* __restrict__ cb1, const float* __restrict__ cg1, const float* __restrict__ cbe1,
    const float* __restrict__ cW2,
    float* __restrict__ agg, float* __restrict__ coord_out, int E)
{
    __shared__ unsigned short Xs[4][16 * XSTR];   // 4 x 4352 B, one slice per wave

    const int wv   = threadIdx.x >> 6;
    const int lane = threadIdx.x & 63;
    const int l15 = lane & 15, quad = lane >> 4;
    const int ge0 = (blockIdx.x * 4 + wv) * 16;
    unsigned short* X = &Xs[wv][0];

    int el  = ge0 + l15;
    int elc = (el < E) ? el : (E - 1);
    int rowl = ei[elc], coll = ei[E + elc];
    float dx = coord[rowl * 3 + 0] - coord[coll * 3 + 0];
    float dy = coord[rowl * 3 + 1] - coord[coll * 3 + 1];
    float dz = coord[rowl * 3 + 2] - coord[coll * 3 + 2];
    float radial = dx * dx + dy * dy + dz * dz;
    float inv = 1.0f / (sqrtf(radial + 1e-8f) + 1.0f);
    float cdx = dx * inv, cdy = dy * inv, cdz = dz * inv;
    float ea = eattr[elc];

    f32x4 acc[8];
    #pragma unroll
    for (int nt = 0; nt < 8; ++nt) acc[nt] = (f32x4){0.f, 0.f, 0.f, 0.f};

    // ---- GEMM1: [16x256] @ eW1f, A direct from global ----
    for (int kb = 0; kb < 8; ++kb) {
        int ko = (kb & 3) * 32 + quad * 8;
        bf16x8 af = *(const bf16x8*)(hb + (size_t)((kb < 4) ? rowl : coll) * H + ko);
        const unsigned short* bp = eW1f + ((size_t)kb * 8) * 512 + (size_t)lane * 8;
        #pragma unroll
        for (int nt = 0; nt < 8; ++nt) {
            bf16x8 bf = *(const bf16x8*)(bp + (size_t)nt * 512);
            acc[nt] = __builtin_amdgcn_mfma_f32_16x16x32_bf16(af, bf, acc[nt], 0, 0, 0);
        }
    }

    // ---- rank-1 fp32 update: k=256 (radial), k=257 (eattr) ----
    {
        float rad_r[4], ea_r[4];
        #pragma unroll
        for (int r = 0; r < 4; ++r) {
            rad_r[r] = __shfl(radial, quad * 4 + r, 64);
            ea_r[r]  = __shfl(ea,     quad * 4 + r, 64);
        }
        #pragma unroll
        for (int nt = 0; nt < 8; ++nt) {
            float w256 = eW1[256 * H + nt * 16 + l15];
            float w257 = eW1[257 * H + nt * 16 + l15];
            #pragma unroll
            for (int r = 0; r < 4; ++r)
                acc[nt][r] += rad_r[r] * w256 + ea_r[r] * w257;
        }
    }

    // ---- epilogue 1 -> X ----
    ln_silu_store1(acc, eb1, eg1, ebe1, X, l15, quad);

    // ---- GEMM2: [16x128] @ eW2f ----
    f32x4 ac2[8];
    #pragma unroll
    for (int nt = 0; nt < 8; ++nt) ac2[nt] = (f32x4){0.f, 0.f, 0.f, 0.f};
    for (int kb = 0; kb < 4; ++kb) {
        bf16x8 af = *(const bf16x8*)&X[l15 * XSTR + kb * 32 + quad * 8];
        const unsigned short* bp = eW2f + ((size_t)kb * 8) * 512 + (size_t)lane * 8;
        #pragma unroll
        for (int nt = 0; nt < 8; ++nt) {
            bf16x8 bf = *(const bf16x8*)(bp + (size_t)nt * 512);
            ac2[nt] = __builtin_amdgcn_mfma_f32_16x16x32_bf16(af, bf, ac2[nt], 0, 0, 0);
        }
    }

    // ---- epilogue 2 = edge_feat -> X; agg atomics ----
    ln_silu_store1(ac2, eb2, eg2, ebe2, X, l15, quad);

    {
        int rowm[4];
        #pragma unroll
        for (int r = 0; r < 4; ++r) rowm[r] = __shfl(rowl, quad * 4 + r, 64);
        #pragma unroll
        for (int nt = 0; nt < 8; ++nt) {
            #pragma unroll
            for (int r = 0; r < 4; ++r) {
                int geh = ge0 + quad * 4 + r;
                if (geh < E)
                    atomicAdd(&agg[(size_t)rowm[r] * H + nt * 16 + l15], ac2[nt][r]);
            }
        }
    }

    // ---- GEMM3: edge_feat @ cW1f ----
    #pragma unroll
    for (int nt = 0; nt < 8; ++nt) acc[nt] = (f32x4){0.f, 0.f, 0.f, 0.f};
    for (int kb = 0; kb < 4; ++kb) {
        bf16x8 af = *(const bf16x8*)&X[l15 * XSTR + kb * 32 + quad * 8];
        const unsigned short* bp = cW1f + ((size_t)kb * 8) * 512 + (size_t)lane * 8;
        #pragma unroll
        for (int nt = 0; nt < 8; ++nt) {
            bf16x8 bf = *(const bf16x8*)(bp + (size_t)nt * 512);
            acc[nt] = __builtin_amdgcn_mfma_f32_16x16x32_bf16(af, bf, acc[nt], 0, 0, 0);
        }
    }

    // ---- epilogue 3: bias + LN + SiLU, dot cW2 -> cm; coord atomics ----
    {
        float s[4] = {0,0,0,0}, q[4] = {0,0,0,0};
        #pragma unroll
        for (int nt = 0; nt < 8; ++nt) {
            float b = cb1[nt * 16 + l15];
            #pragma unroll
            for (int r = 0; r < 4; ++r) {
                float x = acc[nt][r] + b; acc[nt][r] = x; s[r] += x; q[r] += x * x;
            }
        }
        #pragma unroll
        for (int m = 1; m <= 8; m <<= 1) {
            #pragma unroll
            for (int r = 0; r < 4; ++r) {
                s[r] += __shfl_xor(s[r], m, 64); q[r] += __shfl_xor(q[r], m, 64);
            }
        }
        #pragma unroll
        for (int r = 0; r < 4; ++r) {
            float mu = s[r] * 0.0078125f, v = q[r] * 0.0078125f - mu * mu;
            s[r] = mu; q[r] = rsqrtf(v + 1e-5f);
        }
        float cm[4] = {0,0,0,0};
        #pragma unroll
        for (int nt = 0; nt < 8; ++nt) {
            float gg = cg1[nt * 16 + l15], bb = cbe1[nt * 16 + l15];
            float w2 = cW2[nt * 16 + l15];
            #pragma unroll
            for (int r = 0; r < 4; ++r) {
                float a = q[r] * gg, c = bb - s[r] * a;
                cm[r] += silu_f(acc[nt][r] * a + c) * w2;
            }
        }
        #pragma unroll
        for (int m = 1; m <= 8; m <<= 1) {
            #pragma unroll
            for (int r = 0; r < 4; ++r) cm[r] += __shfl_xor(cm[r], m, 64);
        }
        #pragma unroll
        for (int r = 0; r < 4; ++r) {
            int src = quad * 4 + r;
            float cdxr = __shfl(cdx, src, 64);
            float cdyr = __shfl(cdy, src, 64);
            float cdzr = __shfl(cdz, src, 64);
            int rw = __shfl(rowl, src, 64);
            float comp = (l15 == 0) ? cdxr : ((l15 == 1) ? cdyr : cdzr);
            int geh = ge0 + src;
            if (l15 < 3 && geh < E)
                atomicAdd(&coord_out[(size_t)rw * 3 + l15], comp * cm[r]);
        }
    }
}

// ---- node kernel: 256 threads = 4 independent waves, 16 nodes each ----
__global__ __launch_bounds__(256, 4) void node_kernel(
    const unsigned short* __restrict__ hb, const float* __restrict__ h,
    const float* __restrict__ agg,
    const unsigned short* __restrict__ nW1f,
    const float* __restrict__ nb1, const float* __restrict__ ng1, const float* __restrict__ nbe1,
    const unsigned short* __restrict__ nW2f, const float* __restrict__ nb2,
    float* __restrict__ out, int N)
{
    __shared__ unsigned short Xs[4][16 * XSTR];

    const int wv   = threadIdx.x >> 6;
    const int lane = threadIdx.x & 63;
    const int l15 = lane & 15, quad = lane >> 4;
    const int gn0 = (blockIdx.x * 4 + wv) * 16;
    unsigned short* X = &Xs[wv][0];

    if (gn0 >= N) return;
    int nl = gn0 + l15; if (nl >= N) nl = N - 1;

    f32x4 acc[8];
    #pragma unroll
    for (int nt = 0; nt < 8; ++nt) acc[nt] = (f32x4){0.f, 0.f, 0.f, 0.f};

    // ---- GEMM1: [16x256] @ nW1f; k<128 from hb (bf16), k>=128 from agg (fp32, cvt) ----
    for (int kb = 0; kb < 8; ++kb) {
        int ko = (kb & 3) * 32 + quad * 8;
        bf16x8 af = (kb < 4) ? *(const bf16x8*)(hb + (size_t)nl * H + ko)
                             : ld_cvt8(agg + (size_t)nl * H + ko);
        const unsigned short* bp = nW1f + ((size_t)kb * 8) * 512 + (size_t)lane * 8;
        #pragma unroll
        for (int nt = 0; nt < 8; ++nt) {
            bf16x8 bf = *(const bf16x8*)(bp + (size_t)nt * 512);
            acc[nt] = __builtin_amdgcn_mfma_f32_16x16x32_bf16(af, bf, acc[nt], 0, 0, 0);
        }
    }

    ln_silu_store1(acc, nb1, ng1, nbe1, X, l15, quad);

    // ---- GEMM2: @ nW2f ----
    f32x4 ac2[8];
    #pragma unroll
    for (int nt = 0; nt < 8; ++nt) ac2[nt] = (f32x4){0.f, 0.f, 0.f, 0.f};
    for (int kb = 0; kb < 4; ++kb) {
        bf16x8 af = *(const bf16x8*)&X[l15 * XSTR + kb * 32 + quad * 8];
        const unsigned short* bp = nW2f + ((size_t)kb * 8) * 512 + (size_t)lane * 8;
        #pragma unroll
        for (int nt = 0; nt < 8; ++nt) {
            bf16x8 bf = *(const bf16x8*)(bp + (size_t)nt * 512);
            ac2[nt] = __builtin_amdgcn_mfma_f32_16x16x32_bf16(af, bf, ac2[nt], 0, 0, 0);
        }
    }

    // ---- out = h + acc2 + b ----
    #pragma unroll
    for (int nt = 0; nt < 8; ++nt) {
        float b = nb2[nt * 16 + l15];
        #pragma unroll
        for (int r = 0; r < 4; ++r) {
            int gn = gn0 + quad * 4 + r;
            if (gn < N) {
                size_t idx = (size_t)gn * H + nt * 16 + l15;
                out[idx] = ac2[nt][r] + b + h[idx];
            }
        }
    }
}

// -------------------- launch --------------------
extern "C" void kernel_launch(void* const* d_in, const int* in_sizes, int n_in,
                              void* d_out, int out_size, void* d_ws, size_t ws_size,
                              hipStream_t stream) {
    const float* h     = (const float*)d_in[0];
    const int*   ei    = (const int*)d_in[1];
    const float* coord = (const float*)d_in[2];
    const float* eattr = (const float*)d_in[3];
    const float* eW1   = (const float*)d_in[4];
    const float* eb1   = (const float*)d_in[5];
    const float* eg1   = (const float*)d_in[6];
    const float* ebe1  = (const float*)d_in[7];
    const float* eW2   = (const float*)d_in[8];
    const float* eb2   = (const float*)d_in[9];
    const float* eg2   = (const float*)d_in[10];
    const float* ebe2  = (const float*)d_in[11];
    const float* nW1   = (const float*)d_in[12];
    const float* nb1   = (const float*)d_in[13];
    const float* ng1   = (const float*)d_in[14];
    const float* nbe1  = (const float*)d_in[15];
    const float* nW2   = (const float*)d_in[16];
    const float* nb2   = (const float*)d_in[17];
    const float* cW1   = (const float*)d_in[18];
    const float* cb1   = (const float*)d_in[19];
    const float* cg1   = (const float*)d_in[20];
    const float* cbe1  = (const float*)d_in[21];
    const float* cW2   = (const float*)d_in[22];

    const int N = in_sizes[0] / H;
    const int E = in_sizes[1] / 2;

    float* out       = (float*)d_out;
    float* coord_out = out + (size_t)N * H;

    // ---- workspace layout ----
    char* ws = (char*)d_ws;
    size_t o = 0;
    float* agg = (float*)(ws + o);                    o += (size_t)N * H * 4;
    unsigned short* hb   = (unsigned short*)(ws + o); o += (size_t)N * H * 2;
    unsigned short* eW1f = (unsigned short*)(ws + o); o += (size_t)H * KE * 2;
    unsigned short* eW2f = (unsigned short*)(ws + o); o += (size_t)H * H * 2;
    unsigned short* cW1f = (unsigned short*)(ws + o); o += (size_t)H * H * 2;
    unsigned short* nW1f = (unsigned short*)(ws + o); o += (size_t)H * KN * 2;
    unsigned short* nW2f = (unsigned short*)(ws + o); o += (size_t)H * H * 2;

    hipMemsetAsync(agg, 0, (size_t)N * H * sizeof(float), stream);
    hipMemcpyAsync(coord_out, coord, (size_t)N * 3 * sizeof(float),
                   hipMemcpyDeviceToDevice, stream);

    prep_h<<<(N * H / 4 + 255) / 256, 256, 0, stream>>>(h, hb, N * H / 4);
    prep_w_all<<<dim3(64, 5), 64, 0, stream>>>(eW1, eW2, cW1, nW1, nW2,
                                               eW1f, eW2f, cW1f, nW1f, nW2f);

    edge_kernel<<<(E + 63) / 64, 256, 0, stream>>>(
        hb, ei, coord, eattr,
        eW1f, eW1, eb1, eg1, ebe1,
        eW2f, eb2, eg2, ebe2,
        cW1f, cb1, cg1, cbe1, cW2,
        agg, coord_out, E);

    node_kernel<<<(N + 63) / 64, 256, 0, stream>>>(
        hb, h, agg, nW1f, nb1, ng1, nbe1, nW2f, nb2, out, N);
}

// Round 9
// 391.235 us; speedup vs baseline: 1.1568x; 1.0162x over previous
//
#include <hip/hip_runtime.h>
#include <math.h>

#define H 128
#define KE 256      // MFMA K for edge GEMM1 (k=256,257 via fp32 rank-1 update)
#define KN 256      // node GEMM1 K (2H)
#define XSTR 136    // LDS transpose-buffer row stride (elems)

typedef __attribute__((ext_vector_type(8))) short bf16x8;
typedef __attribute__((ext_vector_type(4))) float f32x4;

__device__ __forceinline__ float silu_f(float x) { return x / (1.0f + __expf(-x)); }

__device__ __forceinline__ unsigned short f2bf(float f) {
    unsigned int u = __float_as_uint(f);
    unsigned int r = u + 0x7FFFu + ((u >> 16) & 1u);
    return (unsigned short)(r >> 16);
}

// ---- 16-lane sum reduction via DPP row rotations (no LDS, pure VALU) ----
template<int CTRL>
__device__ __forceinline__ float dpp_add(float x) {
    int t = __builtin_amdgcn_update_dpp(0, __float_as_int(x), CTRL, 0xF, 0xF, true);
    return x + __int_as_float(t);
}
__device__ __forceinline__ float red16(float x) {
    x = dpp_add<0x128>(x);   // row_ror:8
    x = dpp_add<0x124>(x);   // row_ror:4
    x = dpp_add<0x122>(x);   // row_ror:2
    x = dpp_add<0x121>(x);   // row_ror:1
    return x;
}

// load 8 consecutive fp32, convert to bf16x8 fragment
__device__ __forceinline__ bf16x8 ld_cvt8(const float* p) {
    float4 f0 = ((const float4*)p)[0];
    float4 f1 = ((const float4*)p)[1];
    union { bf16x8 v; unsigned short u[8]; } pk;
    pk.u[0] = f2bf(f0.x); pk.u[1] = f2bf(f0.y); pk.u[2] = f2bf(f0.z); pk.u[3] = f2bf(f0.w);
    pk.u[4] = f2bf(f1.x); pk.u[5] = f2bf(f1.y); pk.u[6] = f2bf(f1.z); pk.u[7] = f2bf(f1.w);
    return pk.v;
}

// -------------------- prep: h fp32 -> bf16 (vectorized x4) --------------------
__global__ void prep_h(const float* __restrict__ x, unsigned short* __restrict__ y, int n4) {
    int i = blockIdx.x * 256 + threadIdx.x;
    if (i < n4) {
        float4 f = ((const float4*)x)[i];
        ushort4 o;
        o.x = f2bf(f.x); o.y = f2bf(f.y); o.z = f2bf(f.z); o.w = f2bf(f.w);
        ((ushort4*)y)[i] = o;
    }
}

// ---- prep all weights: W[K][128] fp32 -> fragment-linear Wf[(kb*8+nt)*64+lane][8] ----
__global__ void prep_w_all(
    const float* __restrict__ eW1, const float* __restrict__ eW2,
    const float* __restrict__ cW1, const float* __restrict__ nW1,
    const float* __restrict__ nW2,
    unsigned short* __restrict__ eW1f, unsigned short* __restrict__ eW2f,
    unsigned short* __restrict__ cW1f, unsigned short* __restrict__ nW1f,
    unsigned short* __restrict__ nW2f)
{
    const float* W; unsigned short* Wf; int nfrag;
    switch (blockIdx.y) {
        case 0:  W = eW1; Wf = eW1f; nfrag = 8 * 8 * 64; break;
        case 1:  W = eW2; Wf = eW2f; nfrag = 4 * 8 * 64; break;
        case 2:  W = cW1; Wf = cW1f; nfrag = 4 * 8 * 64; break;
        case 3:  W = nW1; Wf = nW1f; nfrag = 8 * 8 * 64; break;
        default: W = nW2; Wf = nW2f; nfrag = 4 * 8 * 64; break;
    }
    int f = blockIdx.x * 64 + threadIdx.x;
    if (f >= nfrag) return;
    int kb = f >> 9;
    int rem = f & 511;
    int nt = rem >> 6, lane = rem & 63;
    int quad = lane >> 4, l15 = lane & 15;
    int n = nt * 16 + l15, k0 = kb * 32 + quad * 8;
    union { bf16x8 v; unsigned short u[8]; } pk;
    #pragma unroll
    for (int j = 0; j < 8; ++j) pk.u[j] = f2bf(W[(size_t)(k0 + j) * H + n]);
    *(bf16x8*)&Wf[(size_t)f * 8] = pk.v;
}

// ---- single-tile epilogue: bias + LN + SiLU; result left in acc, bf16 copy in LDS ----
__device__ __forceinline__ void ln_silu_store1(
    f32x4* acc, const float* __restrict__ bias, const float* __restrict__ g,
    const float* __restrict__ be, unsigned short* X, int l15, int quad)
{
    float s[4] = {0,0,0,0}, q[4] = {0,0,0,0};
    #pragma unroll
    for (int nt = 0; nt < 8; ++nt) {
        float b = bias[nt * 16 + l15];
        #pragma unroll
        for (int r = 0; r < 4; ++r) {
            float x = acc[nt][r] + b; acc[nt][r] = x; s[r] += x; q[r] += x * x;
        }
    }
    #pragma unroll
    for (int r = 0; r < 4; ++r) { s[r] = red16(s[r]); q[r] = red16(q[r]); }
    #pragma unroll
    for (int r = 0; r < 4; ++r) {
        float mu = s[r] * 0.0078125f, v = q[r] * 0.0078125f - mu * mu;
        s[r] = mu; q[r] = rsqrtf(v + 1e-5f);
    }
    #pragma unroll
    for (int nt = 0; nt < 8; ++nt) {
        float gg = g[nt * 16 + l15], bb = be[nt * 16 + l15];
        #pragma unroll
        for (int r = 0; r < 4; ++r) {
            float a = q[r] * gg, c = bb - s[r] * a;
            float y = silu_f(acc[nt][r] * a + c);
            acc[nt][r] = y;
            X[(quad * 4 + r) * XSTR + nt * 16 + l15] = f2bf(y);
        }
    }
}

// -------------------- edge kernel: 1 wave, 16 edges, barrier-free --------------------
__global__ __launch_bounds__(64, 4) void edge_kernel(
    const unsigned short* __restrict__ hb, const int* __restrict__ ei,
    const float* __restrict__ coord, const float* __restrict__ eattr,
    const unsigned short* __restrict__ eW1f, const float* __restrict__ eW1,
    const float* __restrict__ eb1, const float* __restrict__ eg1, const float* __restrict__ ebe1,
    const unsigned short* __restrict__ eW2f,
    const float* __restrict__ eb2, const float* __restrict__ eg2, const float* __restrict__ ebe2,
    const unsigned short* __restrict__ cW1f,
    const float* __restrict__ cb1, const float* __restrict__ cg1, const float* __restrict__ cbe1,
    const float* __restrict__ cW2,
    float* __restrict__ agg, float* __restrict__ coord_out, int E)
{
    __shared__ unsigned short X[16 * XSTR];   // 4352 B transpose buffer

    const int lane = threadIdx.x;
    const int l15 = lane & 15, quad = lane >> 4;
    const int ge0 = blockIdx.x * 16;

    int el  = ge0 + l15;
    int elc = (el < E) ? el : (E - 1);
    int rowl = ei[elc], coll = ei[E + elc];
    float dx = coord[rowl * 3 + 0] - coord[coll * 3 + 0];
    float dy = coord[rowl * 3 + 1] - coord[coll * 3 + 1];
    float dz = coord[rowl * 3 + 2] - coord[coll * 3 + 2];
    float radial = dx * dx + dy * dy + dz * dz;
    float inv = 1.0f / (sqrtf(radial + 1e-8f) + 1.0f);
    float cdx = dx * inv, cdy = dy * inv, cdz = dz * inv;
    float ea = eattr[elc];

    f32x4 acc[8];
    #pragma unroll
    for (int nt = 0; nt < 8; ++nt) acc[nt] = (f32x4){0.f, 0.f, 0.f, 0.f};

    // ---- GEMM1: [16x256] @ eW1f, A direct from global ----
    for (int kb = 0; kb < 8; ++kb) {
        int ko = (kb & 3) * 32 + quad * 8;
        bf16x8 af = *(const bf16x8*)(hb + (size_t)((kb < 4) ? rowl : coll) * H + ko);
        const unsigned short* bp = eW1f + ((size_t)kb * 8) * 512 + (size_t)lane * 8;
        #pragma unroll
        for (int nt = 0; nt < 8; ++nt) {
            bf16x8 bf = *(const bf16x8*)(bp + (size_t)nt * 512);
            acc[nt] = __builtin_amdgcn_mfma_f32_16x16x32_bf16(af, bf, acc[nt], 0, 0, 0);
        }
    }

    // ---- rank-1 fp32 update: k=256 (radial), k=257 (eattr) ----
    {
        float rad_r[4], ea_r[4];
        #pragma unroll
        for (int r = 0; r < 4; ++r) {
            rad_r[r] = __shfl(radial, quad * 4 + r, 64);
            ea_r[r]  = __shfl(ea,     quad * 4 + r, 64);
        }
        #pragma unroll
        for (int nt = 0; nt < 8; ++nt) {
            float w256 = eW1[256 * H + nt * 16 + l15];
            float w257 = eW1[257 * H + nt * 16 + l15];
            #pragma unroll
            for (int r = 0; r < 4; ++r)
                acc[nt][r] += rad_r[r] * w256 + ea_r[r] * w257;
        }
    }

    // ---- epilogue 1 -> X ----
    ln_silu_store1(acc, eb1, eg1, ebe1, X, l15, quad);

    // ---- GEMM2: [16x128] @ eW2f ----
    f32x4 ac2[8];
    #pragma unroll
    for (int nt = 0; nt < 8; ++nt) ac2[nt] = (f32x4){0.f, 0.f, 0.f, 0.f};
    for (int kb = 0; kb < 4; ++kb) {
        bf16x8 af = *(const bf16x8*)&X[l15 * XSTR + kb * 32 + quad * 8];
        const unsigned short* bp = eW2f + ((size_t)kb * 8) * 512 + (size_t)lane * 8;
        #pragma unroll
        for (int nt = 0; nt < 8; ++nt) {
            bf16x8 bf = *(const bf16x8*)(bp + (size_t)nt * 512);
            ac2[nt] = __builtin_amdgcn_mfma_f32_16x16x32_bf16(af, bf, ac2[nt], 0, 0, 0);
        }
    }

    // ---- epilogue 2 = edge_feat -> X; agg atomics ----
    ln_silu_store1(ac2, eb2, eg2, ebe2, X, l15, quad);

    {
        int rowm[4];
        #pragma unroll
        for (int r = 0; r < 4; ++r) rowm[r] = __shfl(rowl, quad * 4 + r, 64);
        #pragma unroll
        for (int nt = 0; nt < 8; ++nt) {
            #pragma unroll
            for (int r = 0; r < 4; ++r) {
                int geh = ge0 + quad * 4 + r;
                if (geh < E)
                    atomicAdd(&agg[(size_t)rowm[r] * H + nt * 16 + l15], ac2[nt][r]);
            }
        }
    }

    // ---- GEMM3: edge_feat @ cW1f ----
    #pragma unroll
    for (int nt = 0; nt < 8; ++nt) acc[nt] = (f32x4){0.f, 0.f, 0.f, 0.f};
    for (int kb = 0; kb < 4; ++kb) {
        bf16x8 af = *(const bf16x8*)&X[l15 * XSTR + kb * 32 + quad * 8];
        const unsigned short* bp = cW1f + ((size_t)kb * 8) * 512 + (size_t)lane * 8;
        #pragma unroll
        for (int nt = 0; nt < 8; ++nt) {
            bf16x8 bf = *(const bf16x8*)(bp + (size_t)nt * 512);
            acc[nt] = __builtin_amdgcn_mfma_f32_16x16x32_bf16(af, bf, acc[nt], 0, 0, 0);
        }
    }

    // ---- epilogue 3: bias + LN + SiLU, dot cW2 -> cm; coord atomics ----
    {
        float s[4] = {0,0,0,0}, q[4] = {0,0,0,0};
        #pragma unroll
        for (int nt = 0; nt < 8; ++nt) {
            float b = cb1[nt * 16 + l15];
            #pragma unroll
            for (int r = 0; r < 4; ++r) {
                float x = acc[nt][r] + b; acc[nt][r] = x; s[r] += x; q[r] += x * x;
            }
        }
        #pragma unroll
        for (int r = 0; r < 4; ++r) { s[r] = red16(s[r]); q[r] = red16(q[r]); }
        #pragma unroll
        for (int r = 0; r < 4; ++r) {
            float mu = s[r] * 0.0078125f, v = q[r] * 0.0078125f - mu * mu;
            s[r] = mu; q[r] = rsqrtf(v + 1e-5f);
        }
        float cm[4] = {0,0,0,0};
        #pragma unroll
        for (int nt = 0; nt < 8; ++nt) {
            float gg = cg1[nt * 16 + l15], bb = cbe1[nt * 16 + l15];
            float w2 = cW2[nt * 16 + l15];
            #pragma unroll
            for (int r = 0; r < 4; ++r) {
                float a = q[r] * gg, c = bb - s[r] * a;
                cm[r] += silu_f(acc[nt][r] * a + c) * w2;
            }
        }
        #pragma unroll
        for (int r = 0; r < 4; ++r) cm[r] = red16(cm[r]);
        #pragma unroll
        for (int r = 0; r < 4; ++r) {
            int src = quad * 4 + r;
            float cdxr = __shfl(cdx, src, 64);
            float cdyr = __shfl(cdy, src, 64);
            float cdzr = __shfl(cdz, src, 64);
            int rw = __shfl(rowl, src, 64);
            float comp = (l15 == 0) ? cdxr : ((l15 == 1) ? cdyr : cdzr);
            int geh = ge0 + src;
            if (l15 < 3 && geh < E)
                atomicAdd(&coord_out[(size_t)rw * 3 + l15], comp * cm[r]);
        }
    }
}

// ---- node kernel: 256 threads = 4 independent waves, 16 nodes each ----
__global__ __launch_bounds__(256, 4) void node_kernel(
    const unsigned short* __restrict__ hb, const float* __restrict__ h,
    const float* __restrict__ agg,
    const unsigned short* __restrict__ nW1f,
    const float* __restrict__ nb1, const float* __restrict__ ng1, const float* __restrict__ nbe1,
    const unsigned short* __restrict__ nW2f, const float* __restrict__ nb2,
    float* __restrict__ out, int N)
{
    __shared__ unsigned short Xs[4][16 * XSTR];

    const int wv   = threadIdx.x >> 6;
    const int lane = threadIdx.x & 63;
    const int l15 = lane & 15, quad = lane >> 4;
    const int gn0 = (blockIdx.x * 4 + wv) * 16;
    unsigned short* X = &Xs[wv][0];

    if (gn0 >= N) return;
    int nl = gn0 + l15; if (nl >= N) nl = N - 1;

    f32x4 acc[8];
    #pragma unroll
    for (int nt = 0; nt < 8; ++nt) acc[nt] = (f32x4){0.f, 0.f, 0.f, 0.f};

    // ---- GEMM1: [16x256] @ nW1f; k<128 from hb (bf16), k>=128 from agg (fp32, cvt) ----
    for (int kb = 0; kb < 8; ++kb) {
        int ko = (kb & 3) * 32 + quad * 8;
        bf16x8 af = (kb < 4) ? *(const bf16x8*)(hb + (size_t)nl * H + ko)
                             : ld_cvt8(agg + (size_t)nl * H + ko);
        const unsigned short* bp = nW1f + ((size_t)kb * 8) * 512 + (size_t)lane * 8;
        #pragma unroll
        for (int nt = 0; nt < 8; ++nt) {
            bf16x8 bf = *(const bf16x8*)(bp + (size_t)nt * 512);
            acc[nt] = __builtin_amdgcn_mfma_f32_16x16x32_bf16(af, bf, acc[nt], 0, 0, 0);
        }
    }

    ln_silu_store1(acc, nb1, ng1, nbe1, X, l15, quad);

    // ---- GEMM2: @ nW2f ----
    f32x4 ac2[8];
    #pragma unroll
    for (int nt = 0; nt < 8; ++nt) ac2[nt] = (f32x4){0.f, 0.f, 0.f, 0.f};
    for (int kb = 0; kb < 4; ++kb) {
        bf16x8 af = *(const bf16x8*)&X[l15 * XSTR + kb * 32 + quad * 8];
        const unsigned short* bp = nW2f + ((size_t)kb * 8) * 512 + (size_t)lane * 8;
        #pragma unroll
        for (int nt = 0; nt < 8; ++nt) {
            bf16x8 bf = *(const bf16x8*)(bp + (size_t)nt * 512);
            ac2[nt] = __builtin_amdgcn_mfma_f32_16x16x32_bf16(af, bf, ac2[nt], 0, 0, 0);
        }
    }

    // ---- out = h + acc2 + b ----
    #pragma unroll
    for (int nt = 0; nt < 8; ++nt) {
        float b = nb2[nt * 16 + l15];
        #pragma unroll
        for (int r = 0; r < 4; ++r) {
            int gn = gn0 + quad * 4 + r;
            if (gn < N) {
                size_t idx = (size_t)gn * H + nt * 16 + l15;
                out[idx] = ac2[nt][r] + b + h[idx];
            }
        }
    }
}

// -------------------- launch --------------------
extern "C" void kernel_launch(void* const* d_in, const int* in_sizes, int n_in,
                              void* d_out, int out_size, void* d_ws, size_t ws_size,
                              hipStream_t stream) {
    const float* h     = (const float*)d_in[0];
    const int*   ei    = (const int*)d_in[1];
    const float* coord = (const float*)d_in[2];
    const float* eattr = (const float*)d_in[3];
    const float* eW1   = (const float*)d_in[4];
    const float* eb1   = (const float*)d_in[5];
    const float* eg1   = (const float*)d_in[6];
    const float* ebe1  = (const float*)d_in[7];
    const float* eW2   = (const float*)d_in[8];
    const float* eb2   = (const float*)d_in[9];
    const float* eg2   = (const float*)d_in[10];
    const float* ebe2  = (const float*)d_in[11];
    const float* nW1   = (const float*)d_in[12];
    const float* nb1   = (const float*)d_in[13];
    const float* ng1   = (const float*)d_in[14];
    const float* nbe1  = (const float*)d_in[15];
    const float* nW2   = (const float*)d_in[16];
    const float* nb2   = (const float*)d_in[17];
    const float* cW1   = (const float*)d_in[18];
    const float* cb1   = (const float*)d_in[19];
    const float* cg1   = (const float*)d_in[20];
    const float* cbe1  = (const float*)d_in[21];
    const float* cW2   = (const float*)d_in[22];

    const int N = in_sizes[0] / H;
    const int E = in_sizes[1] / 2;

    float* out       = (float*)d_out;
    float* coord_out = out + (size_t)N * H;

    // ---- workspace layout ----
    char* ws = (char*)d_ws;
    size_t o = 0;
    float* agg = (float*)(ws + o);                    o += (size_t)N * H * 4;
    unsigned short* hb   = (unsigned short*)(ws + o); o += (size_t)N * H * 2;
    unsigned short* eW1f = (unsigned short*)(ws + o); o += (size_t)H * KE * 2;
    unsigned short* eW2f = (unsigned short*)(ws + o); o += (size_t)H * H * 2;
    unsigned short* cW1f = (unsigned short*)(ws + o); o += (size_t)H * H * 2;
    unsigned short* nW1f = (unsigned short*)(ws + o); o += (size_t)H * KN * 2;
    unsigned short* nW2f = (unsigned short*)(ws + o); o += (size_t)H * H * 2;

    hipMemsetAsync(agg, 0, (size_t)N * H * sizeof(float), stream);
    hipMemcpyAsync(coord_out, coord, (size_t)N * 3 * sizeof(float),
                   hipMemcpyDeviceToDevice, stream);

    prep_h<<<(N * H / 4 + 255) / 256, 256, 0, stream>>>(h, hb, N * H / 4);
    prep_w_all<<<dim3(64, 5), 64, 0, stream>>>(eW1, eW2, cW1, nW1, nW2,
                                               eW1f, eW2f, cW1f, nW1f, nW2f);

    edge_kernel<<<(E + 15) / 16, 64, 0, stream>>>(
        hb, ei, coord, eattr,
        eW1f, eW1, eb1, eg1, ebe1,
        eW2f, eb2, eg2, ebe2,
        cW1f, cb1, cg1, cbe1, cW2,
        agg, coord_out, E);

    node_kernel<<<(N + 63) / 64, 256, 0, stream>>>(
        hb, h, agg, nW1f, nb1, ng1, nbe1, nW2f, nb2, out, N);
}

// Round 10
// 387.628 us; speedup vs baseline: 1.1675x; 1.0093x over previous
//
#include <hip/hip_runtime.h>
#include <math.h>

#define H 128
#define KE 256      // MFMA K for edge GEMM1 (k=256,257 via fp32 rank-1 update)
#define KN 256      // node GEMM1 K (2H)
#define XSTR 136    // LDS transpose-buffer row stride (elems)

typedef __attribute__((ext_vector_type(8))) short bf16x8;
typedef __attribute__((ext_vector_type(4))) float f32x4;

__device__ __forceinline__ float silu_f(float x) { return x / (1.0f + __expf(-x)); }

__device__ __forceinline__ unsigned short f2bf(float f) {
    unsigned int u = __float_as_uint(f);
    unsigned int r = u + 0x7FFFu + ((u >> 16) & 1u);
    return (unsigned short)(r >> 16);
}

// ---- 16-lane sum reduction via DPP row rotations (no LDS, pure VALU) ----
template<int CTRL>
__device__ __forceinline__ float dpp_add(float x) {
    int t = __builtin_amdgcn_update_dpp(0, __float_as_int(x), CTRL, 0xF, 0xF, true);
    return x + __int_as_float(t);
}
__device__ __forceinline__ float red16(float x) {
    x = dpp_add<0x128>(x);   // row_ror:8
    x = dpp_add<0x124>(x);   // row_ror:4
    x = dpp_add<0x122>(x);   // row_ror:2
    x = dpp_add<0x121>(x);   // row_ror:1
    return x;
}

// load 8 consecutive fp32, convert to bf16x8 fragment
__device__ __forceinline__ bf16x8 ld_cvt8(const float* p) {
    float4 f0 = ((const float4*)p)[0];
    float4 f1 = ((const float4*)p)[1];
    union { bf16x8 v; unsigned short u[8]; } pk;
    pk.u[0] = f2bf(f0.x); pk.u[1] = f2bf(f0.y); pk.u[2] = f2bf(f0.z); pk.u[3] = f2bf(f0.w);
    pk.u[4] = f2bf(f1.x); pk.u[5] = f2bf(f1.y); pk.u[6] = f2bf(f1.z); pk.u[7] = f2bf(f1.w);
    return pk.v;
}

// ---- one weight fragment: W[K][128] fp32 -> fragment-linear Wf[f][8] bf16 ----
__device__ __forceinline__ void wfrag(const float* __restrict__ W,
                                      unsigned short* __restrict__ Wf, int f) {
    int kb = f >> 9, rem = f & 511;
    int nt = rem >> 6, lane = rem & 63;
    int quad = lane >> 4, l15 = lane & 15;
    int n = nt * 16 + l15, k0 = kb * 32 + quad * 8;
    union { bf16x8 v; unsigned short u[8]; } pk;
    #pragma unroll
    for (int j = 0; j < 8; ++j) pk.u[j] = f2bf(W[(size_t)(k0 + j) * H + n]);
    *(bf16x8*)&Wf[(size_t)f * 8] = pk.v;
}

// ---- fused prep: hb convert | agg zero | coord copy | 5 weight transposes ----
// block ranges: [0,b0) hb, [b0,b1) agg, [b1,b2) coord, [b2,...) weight frags
__global__ __launch_bounds__(256) void prep_all(
    const float* __restrict__ h, unsigned short* __restrict__ hb, int n4_h,
    float* __restrict__ agg, int n4_agg,
    const float* __restrict__ coord, float* __restrict__ coord_out, int n_coord,
    const float* __restrict__ eW1, const float* __restrict__ eW2,
    const float* __restrict__ cW1, const float* __restrict__ nW1,
    const float* __restrict__ nW2,
    unsigned short* __restrict__ eW1f, unsigned short* __restrict__ eW2f,
    unsigned short* __restrict__ cW1f, unsigned short* __restrict__ nW1f,
    unsigned short* __restrict__ nW2f,
    int b0, int b1, int b2)
{
    int b = blockIdx.x;
    int t = threadIdx.x;
    if (b < b0) {
        int i = b * 256 + t;
        if (i < n4_h) {
            float4 f = ((const float4*)h)[i];
            ushort4 o;
            o.x = f2bf(f.x); o.y = f2bf(f.y); o.z = f2bf(f.z); o.w = f2bf(f.w);
            ((ushort4*)hb)[i] = o;
        }
    } else if (b < b1) {
        int i = (b - b0) * 256 + t;
        if (i < n4_agg) ((float4*)agg)[i] = (float4){0.f, 0.f, 0.f, 0.f};
    } else if (b < b2) {
        int i = (b - b1) * 256 + t;
        if (i < n_coord) coord_out[i] = coord[i];
    } else {
        int idx = (b - b2) * 256 + t;
        // eW1f: 4096, nW1f: 4096, eW2f: 2048, cW1f: 2048, nW2f: 2048
        if      (idx <  4096) wfrag(eW1, eW1f, idx);
        else if (idx <  8192) wfrag(nW1, nW1f, idx - 4096);
        else if (idx < 10240) wfrag(eW2, eW2f, idx - 8192);
        else if (idx < 12288) wfrag(cW1, cW1f, idx - 10240);
        else if (idx < 14336) wfrag(nW2, nW2f, idx - 12288);
    }
}

// ---- single-tile epilogue: bias + LN + SiLU; result left in acc, bf16 copy in LDS ----
__device__ __forceinline__ void ln_silu_store1(
    f32x4* acc, const float* __restrict__ bias, const float* __restrict__ g,
    const float* __restrict__ be, unsigned short* X, int l15, int quad)
{
    float s[4] = {0,0,0,0}, q[4] = {0,0,0,0};
    #pragma unroll
    for (int nt = 0; nt < 8; ++nt) {
        float b = bias[nt * 16 + l15];
        #pragma unroll
        for (int r = 0; r < 4; ++r) {
            float x = acc[nt][r] + b; acc[nt][r] = x; s[r] += x; q[r] += x * x;
        }
    }
    #pragma unroll
    for (int r = 0; r < 4; ++r) { s[r] = red16(s[r]); q[r] = red16(q[r]); }
    #pragma unroll
    for (int r = 0; r < 4; ++r) {
        float mu = s[r] * 0.0078125f, v = q[r] * 0.0078125f - mu * mu;
        s[r] = mu; q[r] = rsqrtf(v + 1e-5f);
    }
    #pragma unroll
    for (int nt = 0; nt < 8; ++nt) {
        float gg = g[nt * 16 + l15], bb = be[nt * 16 + l15];
        #pragma unroll
        for (int r = 0; r < 4; ++r) {
            float a = q[r] * gg, c = bb - s[r] * a;
            float y = silu_f(acc[nt][r] * a + c);
            acc[nt][r] = y;
            X[(quad * 4 + r) * XSTR + nt * 16 + l15] = f2bf(y);
        }
    }
}

// -------------------- edge kernel: 1 wave, 16 edges, barrier-free --------------------
__global__ __launch_bounds__(64, 4) void edge_kernel(
    const unsigned short* __restrict__ hb, const int* __restrict__ ei,
    const float* __restrict__ coord, const float* __restrict__ eattr,
    const unsigned short* __restrict__ eW1f, const float* __restrict__ eW1,
    const float* __restrict__ eb1, const float* __restrict__ eg1, const float* __restrict__ ebe1,
    const unsigned short* __restrict__ eW2f,
    const float* __restrict__ eb2, const float* __restrict__ eg2, const float* __restrict__ ebe2,
    const unsigned short* __restrict__ cW1f,
    const float* __restrict__ cb1, const float* __restrict__ cg1, const float* __restrict__ cbe1,
    const float* __restrict__ cW2,
    float* __restrict__ agg, float* __restrict__ coord_out, int E)
{
    __shared__ unsigned short X[16 * XSTR];   // 4352 B transpose buffer

    const int lane = threadIdx.x;
    const int l15 = lane & 15, quad = lane >> 4;
    const int ge0 = blockIdx.x * 16;

    int el  = ge0 + l15;
    int elc = (el < E) ? el : (E - 1);
    int rowl = ei[elc], coll = ei[E + elc];
    float dx = coord[rowl * 3 + 0] - coord[coll * 3 + 0];
    float dy = coord[rowl * 3 + 1] - coord[coll * 3 + 1];
    float dz = coord[rowl * 3 + 2] - coord[coll * 3 + 2];
    float radial = dx * dx + dy * dy + dz * dz;
    float inv = 1.0f / (sqrtf(radial + 1e-8f) + 1.0f);
    float cdx = dx * inv, cdy = dy * inv, cdz = dz * inv;
    float ea = eattr[elc];

    f32x4 acc[8];
    #pragma unroll
    for (int nt = 0; nt < 8; ++nt) acc[nt] = (f32x4){0.f, 0.f, 0.f, 0.f};

    // ---- GEMM1: [16x256] @ eW1f, A direct from global ----
    for (int kb = 0; kb < 8; ++kb) {
        int ko = (kb & 3) * 32 + quad * 8;
        bf16x8 af = *(const bf16x8*)(hb + (size_t)((kb < 4) ? rowl : coll) * H + ko);
        const unsigned short* bp = eW1f + ((size_t)kb * 8) * 512 + (size_t)lane * 8;
        #pragma unroll
        for (int nt = 0; nt < 8; ++nt) {
            bf16x8 bf = *(const bf16x8*)(bp + (size_t)nt * 512);
            acc[nt] = __builtin_amdgcn_mfma_f32_16x16x32_bf16(af, bf, acc[nt], 0, 0, 0);
        }
    }

    // ---- rank-1 fp32 update: k=256 (radial), k=257 (eattr) ----
    {
        float rad_r[4], ea_r[4];
        #pragma unroll
        for (int r = 0; r < 4; ++r) {
            rad_r[r] = __shfl(radial, quad * 4 + r, 64);
            ea_r[r]  = __shfl(ea,     quad * 4 + r, 64);
        }
        #pragma unroll
        for (int nt = 0; nt < 8; ++nt) {
            float w256 = eW1[256 * H + nt * 16 + l15];
            float w257 = eW1[257 * H + nt * 16 + l15];
            #pragma unroll
            for (int r = 0; r < 4; ++r)
                acc[nt][r] += rad_r[r] * w256 + ea_r[r] * w257;
        }
    }

    // ---- epilogue 1 -> X ----
    ln_silu_store1(acc, eb1, eg1, ebe1, X, l15, quad);

    // ---- GEMM2: [16x128] @ eW2f ----
    f32x4 ac2[8];
    #pragma unroll
    for (int nt = 0; nt < 8; ++nt) ac2[nt] = (f32x4){0.f, 0.f, 0.f, 0.f};
    for (int kb = 0; kb < 4; ++kb) {
        bf16x8 af = *(const bf16x8*)&X[l15 * XSTR + kb * 32 + quad * 8];
        const unsigned short* bp = eW2f + ((size_t)kb * 8) * 512 + (size_t)lane * 8;
        #pragma unroll
        for (int nt = 0; nt < 8; ++nt) {
            bf16x8 bf = *(const bf16x8*)(bp + (size_t)nt * 512);
            ac2[nt] = __builtin_amdgcn_mfma_f32_16x16x32_bf16(af, bf, ac2[nt], 0, 0, 0);
        }
    }

    // ---- epilogue 2 = edge_feat -> X; agg atomics ----
    ln_silu_store1(ac2, eb2, eg2, ebe2, X, l15, quad);

    {
        int rowm[4];
        #pragma unroll
        for (int r = 0; r < 4; ++r) rowm[r] = __shfl(rowl, quad * 4 + r, 64);
        #pragma unroll
        for (int nt = 0; nt < 8; ++nt) {
            #pragma unroll
            for (int r = 0; r < 4; ++r) {
                int geh = ge0 + quad * 4 + r;
                if (geh < E)
                    atomicAdd(&agg[(size_t)rowm[r] * H + nt * 16 + l15], ac2[nt][r]);
            }
        }
    }

    // ---- GEMM3: edge_feat @ cW1f ----
    #pragma unroll
    for (int nt = 0; nt < 8; ++nt) acc[nt] = (f32x4){0.f, 0.f, 0.f, 0.f};
    for (int kb = 0; kb < 4; ++kb) {
        bf16x8 af = *(const bf16x8*)&X[l15 * XSTR + kb * 32 + quad * 8];
        const unsigned short* bp = cW1f + ((size_t)kb * 8) * 512 + (size_t)lane * 8;
        #pragma unroll
        for (int nt = 0; nt < 8; ++nt) {
            bf16x8 bf = *(const bf16x8*)(bp + (size_t)nt * 512);
            acc[nt] = __builtin_amdgcn_mfma_f32_16x16x32_bf16(af, bf, acc[nt], 0, 0, 0);
        }
    }

    // ---- epilogue 3: bias + LN + SiLU, dot cW2 -> cm; coord atomics ----
    {
        float s[4] = {0,0,0,0}, q[4] = {0,0,0,0};
        #pragma unroll
        for (int nt = 0; nt < 8; ++nt) {
            float b = cb1[nt * 16 + l15];
            #pragma unroll
            for (int r = 0; r < 4; ++r) {
                float x = acc[nt][r] + b; acc[nt][r] = x; s[r] += x; q[r] += x * x;
            }
        }
        #pragma unroll
        for (int r = 0; r < 4; ++r) { s[r] = red16(s[r]); q[r] = red16(q[r]); }
        #pragma unroll
        for (int r = 0; r < 4; ++r) {
            float mu = s[r] * 0.0078125f, v = q[r] * 0.0078125f - mu * mu;
            s[r] = mu; q[r] = rsqrtf(v + 1e-5f);
        }
        float cm[4] = {0,0,0,0};
        #pragma unroll
        for (int nt = 0; nt < 8; ++nt) {
            float gg = cg1[nt * 16 + l15], bb = cbe1[nt * 16 + l15];
            float w2 = cW2[nt * 16 + l15];
            #pragma unroll
            for (int r = 0; r < 4; ++r) {
                float a = q[r] * gg, c = bb - s[r] * a;
                cm[r] += silu_f(acc[nt][r] * a + c) * w2;
            }
        }
        #pragma unroll
        for (int r = 0; r < 4; ++r) cm[r] = red16(cm[r]);
        #pragma unroll
        for (int r = 0; r < 4; ++r) {
            int src = quad * 4 + r;
            float cdxr = __shfl(cdx, src, 64);
            float cdyr = __shfl(cdy, src, 64);
            float cdzr = __shfl(cdz, src, 64);
            int rw = __shfl(rowl, src, 64);
            float comp = (l15 == 0) ? cdxr : ((l15 == 1) ? cdyr : cdzr);
            int geh = ge0 + src;
            if (l15 < 3 && geh < E)
                atomicAdd(&coord_out[(size_t)rw * 3 + l15], comp * cm[r]);
        }
    }
}

// ---- node kernel: 256 threads = 4 independent waves, 16 nodes each ----
__global__ __launch_bounds__(256, 4) void node_kernel(
    const unsigned short* __restrict__ hb, const float* __restrict__ h,
    const float* __restrict__ agg,
    const unsigned short* __restrict__ nW1f,
    const float* __restrict__ nb1, const float* __restrict__ ng1, const float* __restrict__ nbe1,
    const unsigned short* __restrict__ nW2f, const float* __restrict__ nb2,
    float* __restrict__ out, int N)
{
    __shared__ unsigned short Xs[4][16 * XSTR];

    const int wv   = threadIdx.x >> 6;
    const int lane = threadIdx.x & 63;
    const int l15 = lane & 15, quad = lane >> 4;
    const int gn0 = (blockIdx.x * 4 + wv) * 16;
    unsigned short* X = &Xs[wv][0];

    if (gn0 >= N) return;
    int nl = gn0 + l15; if (nl >= N) nl = N - 1;

    f32x4 acc[8];
    #pragma unroll
    for (int nt = 0; nt < 8; ++nt) acc[nt] = (f32x4){0.f, 0.f, 0.f, 0.f};

    // ---- GEMM1: [16x256] @ nW1f; k<128 from hb (bf16), k>=128 from agg (fp32, cvt) ----
    for (int kb = 0; kb < 8; ++kb) {
        int ko = (kb & 3) * 32 + quad * 8;
        bf16x8 af = (kb < 4) ? *(const bf16x8*)(hb + (size_t)nl * H + ko)
                             : ld_cvt8(agg + (size_t)nl * H + ko);
        const unsigned short* bp = nW1f + ((size_t)kb * 8) * 512 + (size_t)lane * 8;
        #pragma unroll
        for (int nt = 0; nt < 8; ++nt) {
            bf16x8 bf = *(const bf16x8*)(bp + (size_t)nt * 512);
            acc[nt] = __builtin_amdgcn_mfma_f32_16x16x32_bf16(af, bf, acc[nt], 0, 0, 0);
        }
    }

    ln_silu_store1(acc, nb1, ng1, nbe1, X, l15, quad);

    // ---- GEMM2: @ nW2f ----
    f32x4 ac2[8];
    #pragma unroll
    for (int nt = 0; nt < 8; ++nt) ac2[nt] = (f32x4){0.f, 0.f, 0.f, 0.f};
    for (int kb = 0; kb < 4; ++kb) {
        bf16x8 af = *(const bf16x8*)&X[l15 * XSTR + kb * 32 + quad * 8];
        const unsigned short* bp = nW2f + ((size_t)kb * 8) * 512 + (size_t)lane * 8;
        #pragma unroll
        for (int nt = 0; nt < 8; ++nt) {
            bf16x8 bf = *(const bf16x8*)(bp + (size_t)nt * 512);
            ac2[nt] = __builtin_amdgcn_mfma_f32_16x16x32_bf16(af, bf, ac2[nt], 0, 0, 0);
        }
    }

    // ---- out = h + acc2 + b ----
    #pragma unroll
    for (int nt = 0; nt < 8; ++nt) {
        float b = nb2[nt * 16 + l15];
        #pragma unroll
        for (int r = 0; r < 4; ++r) {
            int gn = gn0 + quad * 4 + r;
            if (gn < N) {
                size_t idx = (size_t)gn * H + nt * 16 + l15;
                out[idx] = ac2[nt][r] + b + h[idx];
            }
        }
    }
}

// -------------------- launch --------------------
extern "C" void kernel_launch(void* const* d_in, const int* in_sizes, int n_in,
                              void* d_out, int out_size, void* d_ws, size_t ws_size,
                              hipStream_t stream) {
    const float* h     = (const float*)d_in[0];
    const int*   ei    = (const int*)d_in[1];
    const float* coord = (const float*)d_in[2];
    const float* eattr = (const float*)d_in[3];
    const float* eW1   = (const float*)d_in[4];
    const float* eb1   = (const float*)d_in[5];
    const float* eg1   = (const float*)d_in[6];
    const float* ebe1  = (const float*)d_in[7];
    const float* eW2   = (const float*)d_in[8];
    const float* eb2   = (const float*)d_in[9];
    const float* eg2   = (const float*)d_in[10];
    const float* ebe2  = (const float*)d_in[11];
    const float* nW1   = (const float*)d_in[12];
    const float* nb1   = (const float*)d_in[13];
    const float* ng1   = (const float*)d_in[14];
    const float* nbe1  = (const float*)d_in[15];
    const float* nW2   = (const float*)d_in[16];
    const float* nb2   = (const float*)d_in[17];
    const float* cW1   = (const float*)d_in[18];
    const float* cb1   = (const float*)d_in[19];
    const float* cg1   = (const float*)d_in[20];
    const float* cbe1  = (const float*)d_in[21];
    const float* cW2   = (const float*)d_in[22];

    const int N = in_sizes[0] / H;
    const int E = in_sizes[1] / 2;

    float* out       = (float*)d_out;
    float* coord_out = out + (size_t)N * H;

    // ---- workspace layout ----
    char* ws = (char*)d_ws;
    size_t o = 0;
    float* agg = (float*)(ws + o);                    o += (size_t)N * H * 4;
    unsigned short* hb   = (unsigned short*)(ws + o); o += (size_t)N * H * 2;
    unsigned short* eW1f = (unsigned short*)(ws + o); o += (size_t)H * KE * 2;
    unsigned short* eW2f = (unsigned short*)(ws + o); o += (size_t)H * H * 2;
    unsigned short* cW1f = (unsigned short*)(ws + o); o += (size_t)H * H * 2;
    unsigned short* nW1f = (unsigned short*)(ws + o); o += (size_t)H * KN * 2;
    unsigned short* nW2f = (unsigned short*)(ws + o); o += (size_t)H * H * 2;

    // ---- fused prep: hb | agg zero | coord copy | weight frags ----
    const int n4_h   = N * H / 4;
    const int n4_agg = N * H / 4;
    const int n_co   = N * 3;
    const int b0 = (n4_h   + 255) / 256;
    const int b1 = b0 + (n4_agg + 255) / 256;
    const int b2 = b1 + (n_co   + 255) / 256;
    const int bw = (4096 + 4096 + 2048 + 2048 + 2048 + 255) / 256;  // 56
    prep_all<<<b2 + bw, 256, 0, stream>>>(
        h, hb, n4_h, agg, n4_agg, coord, coord_out, n_co,
        eW1, eW2, cW1, nW1, nW2,
        eW1f, eW2f, cW1f, nW1f, nW2f, b0, b1, b2);

    edge_kernel<<<(E + 15) / 16, 64, 0, stream>>>(
        hb, ei, coord, eattr,
        eW1f, eW1, eb1, eg1, ebe1,
        eW2f, eb2, eg2, ebe2,
        cW1f, cb1, cg1, cbe1, cW2,
        agg, coord_out, E);

    node_kernel<<<(N + 63) / 64, 256, 0, stream>>>(
        hb, h, agg, nW1f, nb1, ng1, nbe1, nW2f, nb2, out, N);
}

// Round 11
// 339.546 us; speedup vs baseline: 1.3329x; 1.1416x over previous
//
#include <hip/hip_runtime.h>
#include <math.h>

#define H 128
#define KE 256      // MFMA K for edge GEMM1 (k=256,257 via fp32 rank-1 update)
#define KN 256      // node GEMM1 K (2H)
#define XSTR 136    // LDS transpose-buffer row stride (elems)

typedef __attribute__((ext_vector_type(8))) short bf16x8;
typedef __attribute__((ext_vector_type(4))) float f32x4;

__device__ __forceinline__ float silu_f(float x) { return x / (1.0f + __expf(-x)); }

__device__ __forceinline__ unsigned short f2bf(float f) {
    unsigned int u = __float_as_uint(f);
    unsigned int r = u + 0x7FFFu + ((u >> 16) & 1u);
    return (unsigned short)(r >> 16);
}

// hardware packed-bf16 atomic add (gfx90a+/gfx950), fire-and-forget
__device__ __forceinline__ void atomic_pk_add_bf16(unsigned short* addr, unsigned int pkv) {
    asm volatile("global_atomic_pk_add_bf16 %0, %1, off"
                 :: "v"(addr), "v"(pkv) : "memory");
}

// ---- 16-lane sum reduction via DPP row rotations (no LDS, pure VALU) ----
template<int CTRL>
__device__ __forceinline__ float dpp_add(float x) {
    int t = __builtin_amdgcn_update_dpp(0, __float_as_int(x), CTRL, 0xF, 0xF, true);
    return x + __int_as_float(t);
}
__device__ __forceinline__ float red16(float x) {
    x = dpp_add<0x128>(x);   // row_ror:8
    x = dpp_add<0x124>(x);   // row_ror:4
    x = dpp_add<0x122>(x);   // row_ror:2
    x = dpp_add<0x121>(x);   // row_ror:1
    return x;
}

// ---- one weight fragment: W[K][128] fp32 -> fragment-linear Wf[f][8] bf16 ----
__device__ __forceinline__ void wfrag(const float* __restrict__ W,
                                      unsigned short* __restrict__ Wf, int f) {
    int kb = f >> 9, rem = f & 511;
    int nt = rem >> 6, lane = rem & 63;
    int quad = lane >> 4, l15 = lane & 15;
    int n = nt * 16 + l15, k0 = kb * 32 + quad * 8;
    union { bf16x8 v; unsigned short u[8]; } pk;
    #pragma unroll
    for (int j = 0; j < 8; ++j) pk.u[j] = f2bf(W[(size_t)(k0 + j) * H + n]);
    *(bf16x8*)&Wf[(size_t)f * 8] = pk.v;
}

// ---- fused prep: hb convert | aggb zero (bf16) | coord copy | 5 weight transposes ----
__global__ __launch_bounds__(256) void prep_all(
    const float* __restrict__ h, unsigned short* __restrict__ hb, int n4_h,
    float* __restrict__ aggz, int n4_agg,
    const float* __restrict__ coord, float* __restrict__ coord_out, int n_coord,
    const float* __restrict__ eW1, const float* __restrict__ eW2,
    const float* __restrict__ cW1, const float* __restrict__ nW1,
    const float* __restrict__ nW2,
    unsigned short* __restrict__ eW1f, unsigned short* __restrict__ eW2f,
    unsigned short* __restrict__ cW1f, unsigned short* __restrict__ nW1f,
    unsigned short* __restrict__ nW2f,
    int b0, int b1, int b2)
{
    int b = blockIdx.x;
    int t = threadIdx.x;
    if (b < b0) {
        int i = b * 256 + t;
        if (i < n4_h) {
            float4 f = ((const float4*)h)[i];
            ushort4 o;
            o.x = f2bf(f.x); o.y = f2bf(f.y); o.z = f2bf(f.z); o.w = f2bf(f.w);
            ((ushort4*)hb)[i] = o;
        }
    } else if (b < b1) {
        int i = (b - b0) * 256 + t;
        if (i < n4_agg) ((float4*)aggz)[i] = (float4){0.f, 0.f, 0.f, 0.f};
    } else if (b < b2) {
        int i = (b - b1) * 256 + t;
        if (i < n_coord) coord_out[i] = coord[i];
    } else {
        int idx = (b - b2) * 256 + t;
        if      (idx <  4096) wfrag(eW1, eW1f, idx);
        else if (idx <  8192) wfrag(nW1, nW1f, idx - 4096);
        else if (idx < 10240) wfrag(eW2, eW2f, idx - 8192);
        else if (idx < 12288) wfrag(cW1, cW1f, idx - 10240);
        else if (idx < 14336) wfrag(nW2, nW2f, idx - 12288);
    }
}

// ---- single-tile epilogue: bias + LN + SiLU; result left in acc, bf16 copy in LDS ----
__device__ __forceinline__ void ln_silu_store1(
    f32x4* acc, const float* __restrict__ bias, const float* __restrict__ g,
    const float* __restrict__ be, unsigned short* X, int l15, int quad)
{
    float s[4] = {0,0,0,0}, q[4] = {0,0,0,0};
    #pragma unroll
    for (int nt = 0; nt < 8; ++nt) {
        float b = bias[nt * 16 + l15];
        #pragma unroll
        for (int r = 0; r < 4; ++r) {
            float x = acc[nt][r] + b; acc[nt][r] = x; s[r] += x; q[r] += x * x;
        }
    }
    #pragma unroll
    for (int r = 0; r < 4; ++r) { s[r] = red16(s[r]); q[r] = red16(q[r]); }
    #pragma unroll
    for (int r = 0; r < 4; ++r) {
        float mu = s[r] * 0.0078125f, v = q[r] * 0.0078125f - mu * mu;
        s[r] = mu; q[r] = rsqrtf(v + 1e-5f);
    }
    #pragma unroll
    for (int nt = 0; nt < 8; ++nt) {
        float gg = g[nt * 16 + l15], bb = be[nt * 16 + l15];
        #pragma unroll
        for (int r = 0; r < 4; ++r) {
            float a = q[r] * gg, c = bb - s[r] * a;
            float y = silu_f(acc[nt][r] * a + c);
            acc[nt][r] = y;
            X[(quad * 4 + r) * XSTR + nt * 16 + l15] = f2bf(y);
        }
    }
}

// -------------------- edge kernel: 1 wave, 16 edges, barrier-free --------------------
__global__ __launch_bounds__(64, 4) void edge_kernel(
    const unsigned short* __restrict__ hb, const int* __restrict__ ei,
    const float* __restrict__ coord, const float* __restrict__ eattr,
    const unsigned short* __restrict__ eW1f, const float* __restrict__ eW1,
    const float* __restrict__ eb1, const float* __restrict__ eg1, const float* __restrict__ ebe1,
    const unsigned short* __restrict__ eW2f,
    const float* __restrict__ eb2, const float* __restrict__ eg2, const float* __restrict__ ebe2,
    const unsigned short* __restrict__ cW1f,
    const float* __restrict__ cb1, const float* __restrict__ cg1, const float* __restrict__ cbe1,
    const float* __restrict__ cW2,
    unsigned short* __restrict__ aggb, float* __restrict__ coord_out, int E)
{
    __shared__ unsigned short X[16 * XSTR];   // 4352 B transpose buffer

    const int lane = threadIdx.x;
    const int l15 = lane & 15, quad = lane >> 4;
    const int ge0 = blockIdx.x * 16;

    int el  = ge0 + l15;
    int elc = (el < E) ? el : (E - 1);
    int rowl = ei[elc], coll = ei[E + elc];
    float dx = coord[rowl * 3 + 0] - coord[coll * 3 + 0];
    float dy = coord[rowl * 3 + 1] - coord[coll * 3 + 1];
    float dz = coord[rowl * 3 + 2] - coord[coll * 3 + 2];
    float radial = dx * dx + dy * dy + dz * dz;
    float inv = 1.0f / (sqrtf(radial + 1e-8f) + 1.0f);
    float cdx = dx * inv, cdy = dy * inv, cdz = dz * inv;
    float ea = eattr[elc];

    f32x4 acc[8];
    #pragma unroll
    for (int nt = 0; nt < 8; ++nt) acc[nt] = (f32x4){0.f, 0.f, 0.f, 0.f};

    // ---- GEMM1: [16x256] @ eW1f, A direct from global ----
    for (int kb = 0; kb < 8; ++kb) {
        int ko = (kb & 3) * 32 + quad * 8;
        bf16x8 af = *(const bf16x8*)(hb + (size_t)((kb < 4) ? rowl : coll) * H + ko);
        const unsigned short* bp = eW1f + ((size_t)kb * 8) * 512 + (size_t)lane * 8;
        #pragma unroll
        for (int nt = 0; nt < 8; ++nt) {
            bf16x8 bf = *(const bf16x8*)(bp + (size_t)nt * 512);
            acc[nt] = __builtin_amdgcn_mfma_f32_16x16x32_bf16(af, bf, acc[nt], 0, 0, 0);
        }
    }

    // ---- rank-1 fp32 update: k=256 (radial), k=257 (eattr) ----
    {
        float rad_r[4], ea_r[4];
        #pragma unroll
        for (int r = 0; r < 4; ++r) {
            rad_r[r] = __shfl(radial, quad * 4 + r, 64);
            ea_r[r]  = __shfl(ea,     quad * 4 + r, 64);
        }
        #pragma unroll
        for (int nt = 0; nt < 8; ++nt) {
            float w256 = eW1[256 * H + nt * 16 + l15];
            float w257 = eW1[257 * H + nt * 16 + l15];
            #pragma unroll
            for (int r = 0; r < 4; ++r)
                acc[nt][r] += rad_r[r] * w256 + ea_r[r] * w257;
        }
    }

    // ---- epilogue 1 -> X ----
    ln_silu_store1(acc, eb1, eg1, ebe1, X, l15, quad);

    // ---- GEMM2: [16x128] @ eW2f ----
    f32x4 ac2[8];
    #pragma unroll
    for (int nt = 0; nt < 8; ++nt) ac2[nt] = (f32x4){0.f, 0.f, 0.f, 0.f};
    for (int kb = 0; kb < 4; ++kb) {
        bf16x8 af = *(const bf16x8*)&X[l15 * XSTR + kb * 32 + quad * 8];
        const unsigned short* bp = eW2f + ((size_t)kb * 8) * 512 + (size_t)lane * 8;
        #pragma unroll
        for (int nt = 0; nt < 8; ++nt) {
            bf16x8 bf = *(const bf16x8*)(bp + (size_t)nt * 512);
            ac2[nt] = __builtin_amdgcn_mfma_f32_16x16x32_bf16(af, bf, ac2[nt], 0, 0, 0);
        }
    }

    // ---- epilogue 2 = edge_feat -> X (bf16) ----
    ln_silu_store1(ac2, eb2, eg2, ebe2, X, l15, quad);

    // ---- agg: packed-bf16 atomics, pairs read straight back from X ----
    {
        int rowm[4];
        #pragma unroll
        for (int r = 0; r < 4; ++r) rowm[r] = __shfl(rowl, quad * 4 + r, 64);
        #pragma unroll
        for (int c4 = 0; c4 < 4; ++c4) {        // col pair-group: cols c4*32 + 2*l15 (+1)
            #pragma unroll
            for (int r = 0; r < 4; ++r) {
                int geh = ge0 + quad * 4 + r;
                if (geh < E) {
                    unsigned int pkv =
                        *(const unsigned int*)&X[(quad * 4 + r) * XSTR + c4 * 32 + 2 * l15];
                    atomic_pk_add_bf16(aggb + (size_t)rowm[r] * H + c4 * 32 + 2 * l15, pkv);
                }
            }
        }
    }

    // ---- GEMM3: edge_feat @ cW1f ----
    #pragma unroll
    for (int nt = 0; nt < 8; ++nt) acc[nt] = (f32x4){0.f, 0.f, 0.f, 0.f};
    for (int kb = 0; kb < 4; ++kb) {
        bf16x8 af = *(const bf16x8*)&X[l15 * XSTR + kb * 32 + quad * 8];
        const unsigned short* bp = cW1f + ((size_t)kb * 8) * 512 + (size_t)lane * 8;
        #pragma unroll
        for (int nt = 0; nt < 8; ++nt) {
            bf16x8 bf = *(const bf16x8*)(bp + (size_t)nt * 512);
            acc[nt] = __builtin_amdgcn_mfma_f32_16x16x32_bf16(af, bf, acc[nt], 0, 0, 0);
        }
    }

    // ---- epilogue 3: bias + LN + SiLU, dot cW2 -> cm; coord atomics ----
    {
        float s[4] = {0,0,0,0}, q[4] = {0,0,0,0};
        #pragma unroll
        for (int nt = 0; nt < 8; ++nt) {
            float b = cb1[nt * 16 + l15];
            #pragma unroll
            for (int r = 0; r < 4; ++r) {
                float x = acc[nt][r] + b; acc[nt][r] = x; s[r] += x; q[r] += x * x;
            }
        }
        #pragma unroll
        for (int r = 0; r < 4; ++r) { s[r] = red16(s[r]); q[r] = red16(q[r]); }
        #pragma unroll
        for (int r = 0; r < 4; ++r) {
            float mu = s[r] * 0.0078125f, v = q[r] * 0.0078125f - mu * mu;
            s[r] = mu; q[r] = rsqrtf(v + 1e-5f);
        }
        float cm[4] = {0,0,0,0};
        #pragma unroll
        for (int nt = 0; nt < 8; ++nt) {
            float gg = cg1[nt * 16 + l15], bb = cbe1[nt * 16 + l15];
            float w2 = cW2[nt * 16 + l15];
            #pragma unroll
            for (int r = 0; r < 4; ++r) {
                float a = q[r] * gg, c = bb - s[r] * a;
                cm[r] += silu_f(acc[nt][r] * a + c) * w2;
            }
        }
        #pragma unroll
        for (int r = 0; r < 4; ++r) cm[r] = red16(cm[r]);
        #pragma unroll
        for (int r = 0; r < 4; ++r) {
            int src = quad * 4 + r;
            float cdxr = __shfl(cdx, src, 64);
            float cdyr = __shfl(cdy, src, 64);
            float cdzr = __shfl(cdz, src, 64);
            int rw = __shfl(rowl, src, 64);
            float comp = (l15 == 0) ? cdxr : ((l15 == 1) ? cdyr : cdzr);
            int geh = ge0 + src;
            if (l15 < 3 && geh < E)
                atomicAdd(&coord_out[(size_t)rw * 3 + l15], comp * cm[r]);
        }
    }
}

// ---- node kernel: 256 threads = 4 independent waves, 16 nodes each ----
__global__ __launch_bounds__(256, 4) void node_kernel(
    const unsigned short* __restrict__ hb, const float* __restrict__ h,
    const unsigned short* __restrict__ aggb,
    const unsigned short* __restrict__ nW1f,
    const float* __restrict__ nb1, const float* __restrict__ ng1, const float* __restrict__ nbe1,
    const unsigned short* __restrict__ nW2f, const float* __restrict__ nb2,
    float* __restrict__ out, int N)
{
    __shared__ unsigned short Xs[4][16 * XSTR];

    const int wv   = threadIdx.x >> 6;
    const int lane = threadIdx.x & 63;
    const int l15 = lane & 15, quad = lane >> 4;
    const int gn0 = (blockIdx.x * 4 + wv) * 16;
    unsigned short* X = &Xs[wv][0];

    if (gn0 >= N) return;
    int nl = gn0 + l15; if (nl >= N) nl = N - 1;

    f32x4 acc[8];
    #pragma unroll
    for (int nt = 0; nt < 8; ++nt) acc[nt] = (f32x4){0.f, 0.f, 0.f, 0.f};

    // ---- GEMM1: [16x256] @ nW1f; k<128 from hb, k>=128 from aggb (both bf16) ----
    for (int kb = 0; kb < 8; ++kb) {
        int ko = (kb & 3) * 32 + quad * 8;
        const unsigned short* src = (kb < 4) ? hb : aggb;
        bf16x8 af = *(const bf16x8*)(src + (size_t)nl * H + ko);
        const unsigned short* bp = nW1f + ((size_t)kb * 8) * 512 + (size_t)lane * 8;
        #pragma unroll
        for (int nt = 0; nt < 8; ++nt) {
            bf16x8 bf = *(const bf16x8*)(bp + (size_t)nt * 512);
            acc[nt] = __builtin_amdgcn_mfma_f32_16x16x32_bf16(af, bf, acc[nt], 0, 0, 0);
        }
    }

    ln_silu_store1(acc, nb1, ng1, nbe1, X, l15, quad);

    // ---- GEMM2: @ nW2f ----
    f32x4 ac2[8];
    #pragma unroll
    for (int nt = 0; nt < 8; ++nt) ac2[nt] = (f32x4){0.f, 0.f, 0.f, 0.f};
    for (int kb = 0; kb < 4; ++kb) {
        bf16x8 af = *(const bf16x8*)&X[l15 * XSTR + kb * 32 + quad * 8];
        const unsigned short* bp = nW2f + ((size_t)kb * 8) * 512 + (size_t)lane * 8;
        #pragma unroll
        for (int nt = 0; nt < 8; ++nt) {
            bf16x8 bf = *(const bf16x8*)(bp + (size_t)nt * 512);
            ac2[nt] = __builtin_amdgcn_mfma_f32_16x16x32_bf16(af, bf, ac2[nt], 0, 0, 0);
        }
    }

    // ---- out = h + acc2 + b ----
    #pragma unroll
    for (int nt = 0; nt < 8; ++nt) {
        float b = nb2[nt * 16 + l15];
        #pragma unroll
        for (int r = 0; r < 4; ++r) {
            int gn = gn0 + quad * 4 + r;
            if (gn < N) {
                size_t idx = (size_t)gn * H + nt * 16 + l15;
                out[idx] = ac2[nt][r] + b + h[idx];
            }
        }
    }
}

// -------------------- launch --------------------
extern "C" void kernel_launch(void* const* d_in, const int* in_sizes, int n_in,
                              void* d_out, int out_size, void* d_ws, size_t ws_size,
                              hipStream_t stream) {
    const float* h     = (const float*)d_in[0];
    const int*   ei    = (const int*)d_in[1];
    const float* coord = (const float*)d_in[2];
    const float* eattr = (const float*)d_in[3];
    const float* eW1   = (const float*)d_in[4];
    const float* eb1   = (const float*)d_in[5];
    const float* eg1   = (const float*)d_in[6];
    const float* ebe1  = (const float*)d_in[7];
    const float* eW2   = (const float*)d_in[8];
    const float* eb2   = (const float*)d_in[9];
    const float* eg2   = (const float*)d_in[10];
    const float* ebe2  = (const float*)d_in[11];
    const float* nW1   = (const float*)d_in[12];
    const float* nb1   = (const float*)d_in[13];
    const float* ng1   = (const float*)d_in[14];
    const float* nbe1  = (const float*)d_in[15];
    const float* nW2   = (const float*)d_in[16];
    const float* nb2   = (const float*)d_in[17];
    const float* cW1   = (const float*)d_in[18];
    const float* cb1   = (const float*)d_in[19];
    const float* cg1   = (const float*)d_in[20];
    const float* cbe1  = (const float*)d_in[21];
    const float* cW2   = (const float*)d_in[22];

    const int N = in_sizes[0] / H;
    const int E = in_sizes[1] / 2;

    float* out       = (float*)d_out;
    float* coord_out = out + (size_t)N * H;

    // ---- workspace layout (aggb bf16: N*H*2 bytes) ----
    char* ws = (char*)d_ws;
    size_t o = 0;
    unsigned short* aggb = (unsigned short*)(ws + o); o += (size_t)N * H * 2;
    unsigned short* hb   = (unsigned short*)(ws + o); o += (size_t)N * H * 2;
    unsigned short* eW1f = (unsigned short*)(ws + o); o += (size_t)H * KE * 2;
    unsigned short* eW2f = (unsigned short*)(ws + o); o += (size_t)H * H * 2;
    unsigned short* cW1f = (unsigned short*)(ws + o); o += (size_t)H * H * 2;
    unsigned short* nW1f = (unsigned short*)(ws + o); o += (size_t)H * KN * 2;
    unsigned short* nW2f = (unsigned short*)(ws + o); o += (size_t)H * H * 2;

    // ---- fused prep: hb | aggb zero | coord copy | weight frags ----
    const int n4_h   = N * H / 4;          // float4 groups for hb cvt
    const int n4_agg = N * H / 8;          // float4 (16B) groups over N*H*2 bytes
    const int n_co   = N * 3;
    const int b0 = (n4_h   + 255) / 256;
    const int b1 = b0 + (n4_agg + 255) / 256;
    const int b2 = b1 + (n_co   + 255) / 256;
    const int bw = (4096 + 4096 + 2048 + 2048 + 2048 + 255) / 256;  // 56
    prep_all<<<b2 + bw, 256, 0, stream>>>(
        h, hb, n4_h, (float*)aggb, n4_agg, coord, coord_out, n_co,
        eW1, eW2, cW1, nW1, nW2,
        eW1f, eW2f, cW1f, nW1f, nW2f, b0, b1, b2);

    edge_kernel<<<(E + 15) / 16, 64, 0, stream>>>(
        hb, ei, coord, eattr,
        eW1f, eW1, eb1, eg1, ebe1,
        eW2f, eb2, eg2, ebe2,
        cW1f, cb1, cg1, cbe1, cW2,
        aggb, coord_out, E);

    node_kernel<<<(N + 63) / 64, 256, 0, stream>>>(
        hb, h, aggb, nW1f, nb1, ng1, nbe1, nW2f, nb2, out, N);
}